// Round 1
// baseline (986.272 us; speedup 1.0000x reference)
//
#include <hip/hip_runtime.h>
#include <hip/hip_bf16.h>
#include <math.h>

#define NHEAD 8
#define CDIM 16
#define HCDIM 128
#define NGRAPH 64

// ---------------------------------------------------------------- utilities

__global__ void zero_kernel(int* __restrict__ deg, float* __restrict__ sume,
                            int* __restrict__ cursor, float* __restrict__ gsum, int n) {
    int i = blockIdx.x * 256 + threadIdx.x;
    if (i < n) { deg[i] = 0; sume[i] = 0.f; cursor[i] = 0; }
    if (i < NGRAPH * HCDIM) gsum[i] = 0.f;
}

__global__ void count_deg(const int* __restrict__ dst, const float* __restrict__ eattr,
                          int* __restrict__ deg, float* __restrict__ sume, int E) {
    int e = blockIdx.x * 256 + threadIdx.x;
    if (e >= E) return;
    int d = dst[e];
    atomicAdd(&deg[d], 1);
    atomicAdd(&sume[d], eattr[e]);
}

__global__ void block_sum(const int* __restrict__ deg, int* __restrict__ bsum, int n) {
    __shared__ int s[256];
    int i = blockIdx.x * 256 + threadIdx.x;
    s[threadIdx.x] = (i < n) ? deg[i] : 0;
    __syncthreads();
    for (int off = 128; off > 0; off >>= 1) {
        if (threadIdx.x < off) s[threadIdx.x] += s[threadIdx.x + off];
        __syncthreads();
    }
    if (threadIdx.x == 0) bsum[blockIdx.x] = s[0];
}

__global__ void scan_bsums(int* __restrict__ bsum, int nb) {
    __shared__ int s[512];
    int t = threadIdx.x;
    int v = (t < nb) ? bsum[t] : 0;
    s[t] = v;
    __syncthreads();
    for (int off = 1; off < 512; off <<= 1) {
        int add = (t >= off) ? s[t - off] : 0;
        __syncthreads();
        s[t] += add;
        __syncthreads();
    }
    if (t < nb) bsum[t] = s[t] - v;   // exclusive base per block
}

__global__ void scan_final(const int* __restrict__ deg, const int* __restrict__ bbase,
                           int* __restrict__ eoff, int n) {
    __shared__ int s[256];
    int i = blockIdx.x * 256 + threadIdx.x;
    int v = (i < n) ? deg[i] : 0;
    s[threadIdx.x] = v;
    __syncthreads();
    for (int off = 1; off < 256; off <<= 1) {
        int add = (threadIdx.x >= off) ? s[threadIdx.x - off] : 0;
        __syncthreads();
        s[threadIdx.x] += add;
        __syncthreads();
    }
    if (i < n) eoff[i + 1] = bbase[blockIdx.x] + s[threadIdx.x];
    if (i == 0) eoff[0] = 0;
}

__global__ void scatter_edges(const int* __restrict__ dst, const int* __restrict__ eoff,
                              int* __restrict__ cursor, int* __restrict__ eids, int E) {
    int e = blockIdx.x * 256 + threadIdx.x;
    if (e >= E) return;
    int d = dst[e];
    int p = eoff[d] + atomicAdd(&cursor[d], 1);
    eids[p] = e;
}

__global__ void compute_loop_attr(const int* __restrict__ deg, const float* __restrict__ sume,
                                  float* __restrict__ floop, int n) {
    int i = blockIdx.x * 256 + threadIdx.x;
    if (i < n) floop[i] = sume[i] / fmaxf((float)deg[i], 1.f);
}

__global__ void kcoef_kernel(const float* __restrict__ we1, const float* __restrict__ ae1,
                             const float* __restrict__ we2, const float* __restrict__ ae2,
                             const float* __restrict__ we3, const float* __restrict__ ae3,
                             float* __restrict__ kc) {
    int t = threadIdx.x;
    if (t >= 24) return;
    int l = t >> 3, h = t & 7;
    const float* we = (l == 0) ? we1 : ((l == 1) ? we2 : we3);
    const float* ae = (l == 0) ? ae1 : ((l == 1) ? ae2 : ae3);
    float s = 0.f;
    for (int c = 0; c < CDIM; ++c) s += we[h * CDIM + c] * ae[h * CDIM + c];
    kc[t] = s;
}

__global__ void graph_bounds(const int* __restrict__ batch, int* __restrict__ gstart, int n) {
    int g = threadIdx.x;
    if (g > NGRAPH) return;
    int lo = 0, hi = n;
    while (lo < hi) {
        int mid = (lo + hi) >> 1;
        if (batch[mid] < g) lo = mid + 1; else hi = mid;
    }
    gstart[g] = lo;
}

// ---------------------------------------------------------------- dense lins

// layer 1: [n,4] @ [4,128]
__global__ __launch_bounds__(256) void lin4_128(const float* __restrict__ X,
                                                const float* __restrict__ W,
                                                float* __restrict__ Y, int n) {
    int gid = blockIdx.x * 256 + threadIdx.x;
    int node = gid >> 6;
    if (node >= n) return;
    int lane = gid & 63;
    int c0 = lane * 2;
    float4 xv = *(const float4*)(X + (long)node * 4);
    float a0 = xv.x * W[c0]       + xv.y * W[128 + c0]     + xv.z * W[256 + c0]     + xv.w * W[384 + c0];
    float a1 = xv.x * W[c0 + 1]   + xv.y * W[128 + c0 + 1] + xv.z * W[256 + c0 + 1] + xv.w * W[384 + c0 + 1];
    *(float2*)(Y + (long)node * HCDIM + c0) = make_float2(a0, a1);
}

// layers 2/3: [n,128] @ [128,128], fp32, W staged in LDS.
// wave = 16 rows (two half-waves x 8 rows), lane handles 4 cols.
__global__ __launch_bounds__(256) void gemm_128x128(const float* __restrict__ X,
                                                    const float* __restrict__ W,
                                                    float* __restrict__ Y, int n) {
    __shared__ float sW[HCDIM * HCDIM];   // 64 KB
    for (int i = threadIdx.x * 4; i < HCDIM * HCDIM; i += 256 * 4)
        *(float4*)(sW + i) = *(const float4*)(W + i);
    __syncthreads();

    const int lane = threadIdx.x & 63;
    const int wave = threadIdx.x >> 6;
    const int half = lane >> 5;       // row-group within wave
    const int l5   = lane & 31;
    const int c0   = l5 * 4;          // 4 contiguous cols
    const int rowbase = (blockIdx.x * 4 + wave) * 16 + half * 8;

    float acc[8][4];
#pragma unroll
    for (int r = 0; r < 8; ++r)
#pragma unroll
        for (int j = 0; j < 4; ++j) acc[r][j] = 0.f;

#pragma unroll 2
    for (int k4 = 0; k4 < HCDIM; k4 += 4) {
        float4 xv[8];
#pragma unroll
        for (int r = 0; r < 8; ++r) {
            int row = rowbase + r;
            row = (row < n) ? row : (n - 1);
            xv[r] = *(const float4*)(X + (long)row * HCDIM + k4);
        }
#pragma unroll
        for (int j = 0; j < 4; ++j) {
            float4 wv = *(const float4*)(sW + (k4 + j) * HCDIM + c0);
#pragma unroll
            for (int r = 0; r < 8; ++r) {
                float xs = (j == 0) ? xv[r].x : (j == 1) ? xv[r].y : (j == 2) ? xv[r].z : xv[r].w;
                acc[r][0] += xs * wv.x;
                acc[r][1] += xs * wv.y;
                acc[r][2] += xs * wv.z;
                acc[r][3] += xs * wv.w;
            }
        }
    }
#pragma unroll
    for (int r = 0; r < 8; ++r) {
        int row = rowbase + r;
        if (row < n)
            *(float4*)(Y + (long)row * HCDIM + c0) =
                make_float4(acc[r][0], acc[r][1], acc[r][2], acc[r][3]);
    }
}

// ---------------------------------------------------------------- attention

// asrc[n,h] = sum_c h[n,h,c]*as[h,c] ; adst likewise
__global__ __launch_bounds__(256) void attn_coeff(const float* __restrict__ H,
                                                  const float* __restrict__ as_,
                                                  const float* __restrict__ ad_,
                                                  float* __restrict__ asrc,
                                                  float* __restrict__ adst, int n) {
    int gid = blockIdx.x * 256 + threadIdx.x;
    int node = gid >> 3;
    if (node >= n) return;
    int h = gid & 7;
    const float* hp = H + (long)node * HCDIM + h * CDIM;
    float s = 0.f, d = 0.f;
#pragma unroll
    for (int q = 0; q < 4; ++q) {
        float4 hv = *(const float4*)(hp + q * 4);
        float4 av = *(const float4*)(as_ + h * CDIM + q * 4);
        float4 dv = *(const float4*)(ad_ + h * CDIM + q * 4);
        s += hv.x * av.x + hv.y * av.y + hv.z * av.z + hv.w * av.w;
        d += hv.x * dv.x + hv.y * dv.y + hv.z * dv.z + hv.w * dv.w;
    }
    asrc[node * NHEAD + h] = s;
    adst[node * NHEAD + h] = d;
}

// one wave per dst node: pass1 max, pass2 fused num/den accumulate.
__global__ __launch_bounds__(256) void gat_aggregate(
    const float* __restrict__ hlin,     // [n,128]
    const float* __restrict__ asrc,     // [n,8]
    const float* __restrict__ adst,     // [n,8]
    const int*   __restrict__ srcs,     // [E]
    const float* __restrict__ eattr,    // [E]
    const int*   __restrict__ eoff,     // [n+1]
    const int*   __restrict__ eids,     // [E]
    const float* __restrict__ kc,       // [8] this layer
    const float* __restrict__ bias,     // [128]
    const float* __restrict__ floop,    // [n] (self-loop attr) or unused
    float* __restrict__ out,            // [n,128]
    int n, int use_loop) {
    int wid = (blockIdx.x * 256 + threadIdx.x) >> 6;
    if (wid >= n) return;
    const int lane = threadIdx.x & 63;
    const int h = lane >> 3;
    const int c0 = lane * 2;
    const int nid = wid;

    const float adst_h = adst[nid * NHEAD + h];
    const float k_h = kc[h];
    const int e0 = eoff[nid], e1 = eoff[nid + 1];

    // pass 1: per-head max of leaky_relu(alpha)
    float mx = -INFINITY;
    for (int i = e0; i < e1; ++i) {
        int e = eids[i];
        int s = srcs[e];
        float a = asrc[s * NHEAD + h] + adst_h + eattr[e] * k_h;
        a = (a > 0.f) ? a : 0.2f * a;
        mx = fmaxf(mx, a);
    }
    if (use_loop) {
        float a = asrc[nid * NHEAD + h] + adst_h + floop[nid] * k_h;
        a = (a > 0.f) ? a : 0.2f * a;
        mx = fmaxf(mx, a);
    }

    // pass 2: fused numerator (h[src]*exp) and denominator (exp) accumulation
    float den = 0.f, acc0 = 0.f, acc1 = 0.f;
    for (int i = e0; i < e1; ++i) {
        int e = eids[i];
        int s = srcs[e];
        float a = asrc[s * NHEAD + h] + adst_h + eattr[e] * k_h;
        a = (a > 0.f) ? a : 0.2f * a;
        float w = __expf(a - mx);
        den += w;
        float2 hv = *(const float2*)(hlin + (long)s * HCDIM + c0);
        acc0 += hv.x * w;
        acc1 += hv.y * w;
    }
    if (use_loop) {
        float a = asrc[nid * NHEAD + h] + adst_h + floop[nid] * k_h;
        a = (a > 0.f) ? a : 0.2f * a;
        float w = __expf(a - mx);
        den += w;
        float2 hv = *(const float2*)(hlin + (long)nid * HCDIM + c0);
        acc0 += hv.x * w;
        acc1 += hv.y * w;
    }
    float inv = 1.f / (den + 1e-16f);
    float o0 = fmaxf(acc0 * inv + bias[c0], 0.f);       // + b, relu
    float o1 = fmaxf(acc1 * inv + bias[c0 + 1], 0.f);
    *(float2*)(out + (long)nid * HCDIM + c0) = make_float2(o0, o1);
}

// ---------------------------------------------------------------- pool + MLP

// batch is sorted: register-run accumulate per column, flush on graph change.
__global__ __launch_bounds__(128) void pool_kernel(const float* __restrict__ H,
                                                   const int* __restrict__ batch,
                                                   float* __restrict__ gsum, int n) {
    const int c = threadIdx.x;            // 0..127
    const int n0 = blockIdx.x * 128;
    if (n0 >= n) return;
    const int n1 = min(n0 + 128, n);
    float acc = 0.f;
    int cg = batch[n0];
    for (int i = n0; i < n1; ++i) {
        int g = batch[i];
        if (g != cg) {
            atomicAdd(&gsum[cg * HCDIM + c], acc);
            acc = 0.f;
            cg = g;
        }
        acc += H[(long)i * HCDIM + c];
    }
    atomicAdd(&gsum[cg * HCDIM + c], acc);
}

__global__ __launch_bounds__(64) void mlp_kernel(const float* __restrict__ gsum,
                                                 const int* __restrict__ gstart,
                                                 const float* __restrict__ fw1,
                                                 const float* __restrict__ fb1,
                                                 const float* __restrict__ fw2,
                                                 const float* __restrict__ fb2,
                                                 float* __restrict__ out) {
    const int g = blockIdx.x;
    const int j = threadIdx.x;            // 0..63
    __shared__ float emb[HCDIM];
    __shared__ float gh[64];
    int cnt = gstart[g + 1] - gstart[g];
    float invc = 1.f / fmaxf((float)cnt, 1.f);
    emb[j] = gsum[g * HCDIM + j] * invc;
    emb[j + 64] = gsum[g * HCDIM + 64 + j] * invc;
    __syncthreads();
    float a = fb1[j];
    for (int k = 0; k < HCDIM; ++k) a += emb[k] * fw1[k * 64 + j];
    gh[j] = fmaxf(a, 0.f);
    __syncthreads();
    if (j < 2) {
        float o = fb2[j];
        for (int k = 0; k < 64; ++k) o += gh[k] * fw2[k * 2 + j];
        out[g * 2 + j] = o;
    }
}

// ---------------------------------------------------------------- launcher

extern "C" void kernel_launch(void* const* d_in, const int* in_sizes, int n_in,
                              void* d_out, int out_size, void* d_ws, size_t ws_size,
                              hipStream_t stream) {
    const float* x     = (const float*)d_in[0];
    const int*   eidx  = (const int*)d_in[1];
    const float* eattr = (const float*)d_in[2];
    const int*   batch = (const int*)d_in[3];
    const float* w1  = (const float*)d_in[4];
    const float* as1 = (const float*)d_in[5];
    const float* ad1 = (const float*)d_in[6];
    const float* we1 = (const float*)d_in[7];
    const float* ae1 = (const float*)d_in[8];
    const float* b1  = (const float*)d_in[9];
    const float* w2  = (const float*)d_in[10];
    const float* as2 = (const float*)d_in[11];
    const float* ad2 = (const float*)d_in[12];
    const float* we2 = (const float*)d_in[13];
    const float* ae2 = (const float*)d_in[14];
    const float* b2  = (const float*)d_in[15];
    const float* w3  = (const float*)d_in[16];
    const float* as3 = (const float*)d_in[17];
    const float* ad3 = (const float*)d_in[18];
    const float* we3 = (const float*)d_in[19];
    const float* ae3 = (const float*)d_in[20];
    const float* b3  = (const float*)d_in[21];
    const float* fw1 = (const float*)d_in[22];
    const float* fb1 = (const float*)d_in[23];
    const float* fw2 = (const float*)d_in[24];
    const float* fb2 = (const float*)d_in[25];

    const int N = in_sizes[3];        // batch is [N]
    const int E = in_sizes[2];        // edge_attr is [E,1]
    const int* src = eidx;
    const int* dst = eidx + E;

    // workspace carve
    char* p = (char*)d_ws;
    auto alloc = [&](size_t bytes) {
        void* r = (void*)p;
        p += (bytes + 255) & ~(size_t)255;
        return r;
    };
    float* A      = (float*)alloc((size_t)N * HCDIM * 4);
    float* B      = (float*)alloc((size_t)N * HCDIM * 4);
    float* asrc   = (float*)alloc((size_t)N * NHEAD * 4);
    float* adst   = (float*)alloc((size_t)N * NHEAD * 4);
    int*   deg    = (int*)alloc((size_t)N * 4);
    int*   eoff   = (int*)alloc((size_t)(N + 1) * 4);
    int*   cursor = (int*)alloc((size_t)N * 4);
    int*   eids   = (int*)alloc((size_t)E * 4);
    float* sume   = (float*)alloc((size_t)N * 4);
    float* floop  = (float*)alloc((size_t)N * 4);
    int*   bsum   = (int*)alloc(((size_t)(N + 255) / 256) * 4);
    float* kc     = (float*)alloc(24 * 4);
    int*   gstart = (int*)alloc((NGRAPH + 1) * 4);
    float* gsum   = (float*)alloc(NGRAPH * HCDIM * 4);

    const int NB = (N + 255) / 256;
    const int EB = (E + 255) / 256;
    const int WAVE_BLOCKS = (N * 64 + 255) / 256;   // one wave per node

    // graph structure (identical every call; inputs restored before each launch)
    zero_kernel<<<NB, 256, 0, stream>>>(deg, sume, cursor, gsum, N);
    count_deg<<<EB, 256, 0, stream>>>(dst, eattr, deg, sume, E);
    block_sum<<<NB, 256, 0, stream>>>(deg, bsum, N);
    scan_bsums<<<1, 512, 0, stream>>>(bsum, NB);
    scan_final<<<NB, 256, 0, stream>>>(deg, bsum, eoff, N);
    scatter_edges<<<EB, 256, 0, stream>>>(dst, eoff, cursor, eids, E);
    compute_loop_attr<<<NB, 256, 0, stream>>>(deg, sume, floop, N);
    kcoef_kernel<<<1, 32, 0, stream>>>(we1, ae1, we2, ae2, we3, ae3, kc);
    graph_bounds<<<1, 128, 0, stream>>>(batch, gstart, N);

    // layer 1 (no self loops)
    lin4_128<<<(N * 64 + 255) / 256, 256, 0, stream>>>(x, w1, A, N);
    attn_coeff<<<(N * 8 + 255) / 256, 256, 0, stream>>>(A, as1, ad1, asrc, adst, N);
    gat_aggregate<<<WAVE_BLOCKS, 256, 0, stream>>>(A, asrc, adst, src, eattr, eoff, eids,
                                                   kc + 0, b1, floop, B, N, 0);
    // layer 2 (self loops, fill=mean)
    gemm_128x128<<<(N + 63) / 64, 256, 0, stream>>>(B, w2, A, N);
    attn_coeff<<<(N * 8 + 255) / 256, 256, 0, stream>>>(A, as2, ad2, asrc, adst, N);
    gat_aggregate<<<WAVE_BLOCKS, 256, 0, stream>>>(A, asrc, adst, src, eattr, eoff, eids,
                                                   kc + 8, b2, floop, B, N, 1);
    // layer 3
    gemm_128x128<<<(N + 63) / 64, 256, 0, stream>>>(B, w3, A, N);
    attn_coeff<<<(N * 8 + 255) / 256, 256, 0, stream>>>(A, as3, ad3, asrc, adst, N);
    gat_aggregate<<<WAVE_BLOCKS, 256, 0, stream>>>(A, asrc, adst, src, eattr, eoff, eids,
                                                   kc + 16, b3, floop, B, N, 1);

    // mean-pool + MLP head
    pool_kernel<<<(N + 127) / 128, 128, 0, stream>>>(B, batch, gsum, N);
    mlp_kernel<<<NGRAPH, 64, 0, stream>>>(gsum, gstart, fw1, fb1, fw2, fb2, (float*)d_out);
}

// Round 2
// 675.397 us; speedup vs baseline: 1.4603x; 1.4603x over previous
//
#include <hip/hip_runtime.h>
#include <hip/hip_bf16.h>
#include <math.h>

#define NHEAD 8
#define CDIM 16
#define HCDIM 128
#define NGRAPH 64

// ---------------------------------------------------------------- utilities

__global__ void zero_kernel(int* __restrict__ deg, float* __restrict__ sume,
                            int* __restrict__ cursor, float* __restrict__ gsum, int n) {
    int i = blockIdx.x * 256 + threadIdx.x;
    if (i < n) { deg[i] = 0; sume[i] = 0.f; cursor[i] = 0; }
    if (i < NGRAPH * HCDIM) gsum[i] = 0.f;
}

__global__ void count_deg(const int* __restrict__ dst, const float* __restrict__ eattr,
                          int* __restrict__ deg, float* __restrict__ sume, int E) {
    int e = blockIdx.x * 256 + threadIdx.x;
    if (e >= E) return;
    int d = dst[e];
    atomicAdd(&deg[d], 1);
    atomicAdd(&sume[d], eattr[e]);
}

__global__ void block_sum(const int* __restrict__ deg, int* __restrict__ bsum, int n) {
    __shared__ int s[256];
    int i = blockIdx.x * 256 + threadIdx.x;
    s[threadIdx.x] = (i < n) ? deg[i] : 0;
    __syncthreads();
    for (int off = 128; off > 0; off >>= 1) {
        if (threadIdx.x < off) s[threadIdx.x] += s[threadIdx.x + off];
        __syncthreads();
    }
    if (threadIdx.x == 0) bsum[blockIdx.x] = s[0];
}

__global__ void scan_bsums(int* __restrict__ bsum, int nb) {
    __shared__ int s[512];
    int t = threadIdx.x;
    int v = (t < nb) ? bsum[t] : 0;
    s[t] = v;
    __syncthreads();
    for (int off = 1; off < 512; off <<= 1) {
        int add = (t >= off) ? s[t - off] : 0;
        __syncthreads();
        s[t] += add;
        __syncthreads();
    }
    if (t < nb) bsum[t] = s[t] - v;   // exclusive base per block
}

__global__ void scan_final(const int* __restrict__ deg, const int* __restrict__ bbase,
                           int* __restrict__ eoff, int n) {
    __shared__ int s[256];
    int i = blockIdx.x * 256 + threadIdx.x;
    int v = (i < n) ? deg[i] : 0;
    s[threadIdx.x] = v;
    __syncthreads();
    for (int off = 1; off < 256; off <<= 1) {
        int add = (threadIdx.x >= off) ? s[threadIdx.x - off] : 0;
        __syncthreads();
        s[threadIdx.x] += add;
        __syncthreads();
    }
    if (i < n) eoff[i + 1] = bbase[blockIdx.x] + s[threadIdx.x];
    if (i == 0) eoff[0] = 0;
}

// writes dst-sorted packed edges: epack[p] = {src, bits(eattr)}
__global__ void scatter_edges(const int* __restrict__ src, const int* __restrict__ dst,
                              const float* __restrict__ eattr,
                              const int* __restrict__ eoff,
                              int* __restrict__ cursor, int2* __restrict__ epack, int E) {
    int e = blockIdx.x * 256 + threadIdx.x;
    if (e >= E) return;
    int d = dst[e];
    int p = eoff[d] + atomicAdd(&cursor[d], 1);
    epack[p] = make_int2(src[e], __float_as_int(eattr[e]));
}

__global__ void compute_loop_attr(const int* __restrict__ deg, const float* __restrict__ sume,
                                  float* __restrict__ floop, int n) {
    int i = blockIdx.x * 256 + threadIdx.x;
    if (i < n) floop[i] = sume[i] / fmaxf((float)deg[i], 1.f);
}

__global__ void kcoef_kernel(const float* __restrict__ we1, const float* __restrict__ ae1,
                             const float* __restrict__ we2, const float* __restrict__ ae2,
                             const float* __restrict__ we3, const float* __restrict__ ae3,
                             float* __restrict__ kc) {
    int t = threadIdx.x;
    if (t >= 24) return;
    int l = t >> 3, h = t & 7;
    const float* we = (l == 0) ? we1 : ((l == 1) ? we2 : we3);
    const float* ae = (l == 0) ? ae1 : ((l == 1) ? ae2 : ae3);
    float s = 0.f;
    for (int c = 0; c < CDIM; ++c) s += we[h * CDIM + c] * ae[h * CDIM + c];
    kc[t] = s;
}

__global__ void graph_bounds(const int* __restrict__ batch, int* __restrict__ gstart, int n) {
    int g = threadIdx.x;
    if (g > NGRAPH) return;
    int lo = 0, hi = n;
    while (lo < hi) {
        int mid = (lo + hi) >> 1;
        if (batch[mid] < g) lo = mid + 1; else hi = mid;
    }
    gstart[g] = lo;
}

// ---------------------------------------------------------------- dense lins

// layer 1: [n,4] @ [4,128]
__global__ __launch_bounds__(256) void lin4_128(const float* __restrict__ X,
                                                const float* __restrict__ W,
                                                float* __restrict__ Y, int n) {
    int gid = blockIdx.x * 256 + threadIdx.x;
    int node = gid >> 6;
    if (node >= n) return;
    int lane = gid & 63;
    int c0 = lane * 2;
    float4 xv = *(const float4*)(X + (long)node * 4);
    float a0 = xv.x * W[c0]       + xv.y * W[128 + c0]     + xv.z * W[256 + c0]     + xv.w * W[384 + c0];
    float a1 = xv.x * W[c0 + 1]   + xv.y * W[128 + c0 + 1] + xv.z * W[256 + c0 + 1] + xv.w * W[384 + c0 + 1];
    *(float2*)(Y + (long)node * HCDIM + c0) = make_float2(a0, a1);
}

// layers 2/3: [n,128] @ [128,128], fp32, W staged in LDS.
__global__ __launch_bounds__(256) void gemm_128x128(const float* __restrict__ X,
                                                    const float* __restrict__ W,
                                                    float* __restrict__ Y, int n) {
    __shared__ float sW[HCDIM * HCDIM];   // 64 KB
    for (int i = threadIdx.x * 4; i < HCDIM * HCDIM; i += 256 * 4)
        *(float4*)(sW + i) = *(const float4*)(W + i);
    __syncthreads();

    const int lane = threadIdx.x & 63;
    const int wave = threadIdx.x >> 6;
    const int half = lane >> 5;       // row-group within wave
    const int l5   = lane & 31;
    const int c0   = l5 * 4;          // 4 contiguous cols
    const int rowbase = (blockIdx.x * 4 + wave) * 16 + half * 8;

    float acc[8][4];
#pragma unroll
    for (int r = 0; r < 8; ++r)
#pragma unroll
        for (int j = 0; j < 4; ++j) acc[r][j] = 0.f;

#pragma unroll 2
    for (int k4 = 0; k4 < HCDIM; k4 += 4) {
        float4 xv[8];
#pragma unroll
        for (int r = 0; r < 8; ++r) {
            int row = rowbase + r;
            row = (row < n) ? row : (n - 1);
            xv[r] = *(const float4*)(X + (long)row * HCDIM + k4);
        }
#pragma unroll
        for (int j = 0; j < 4; ++j) {
            float4 wv = *(const float4*)(sW + (k4 + j) * HCDIM + c0);
#pragma unroll
            for (int r = 0; r < 8; ++r) {
                float xs = (j == 0) ? xv[r].x : (j == 1) ? xv[r].y : (j == 2) ? xv[r].z : xv[r].w;
                acc[r][0] += xs * wv.x;
                acc[r][1] += xs * wv.y;
                acc[r][2] += xs * wv.z;
                acc[r][3] += xs * wv.w;
            }
        }
    }
#pragma unroll
    for (int r = 0; r < 8; ++r) {
        int row = rowbase + r;
        if (row < n)
            *(float4*)(Y + (long)row * HCDIM + c0) =
                make_float4(acc[r][0], acc[r][1], acc[r][2], acc[r][3]);
    }
}

// ---------------------------------------------------------------- attention

__global__ __launch_bounds__(256) void attn_coeff(const float* __restrict__ H,
                                                  const float* __restrict__ as_,
                                                  const float* __restrict__ ad_,
                                                  float* __restrict__ asrc,
                                                  float* __restrict__ adst, int n) {
    int gid = blockIdx.x * 256 + threadIdx.x;
    int node = gid >> 3;
    if (node >= n) return;
    int h = gid & 7;
    const float* hp = H + (long)node * HCDIM + h * CDIM;
    float s = 0.f, d = 0.f;
#pragma unroll
    for (int q = 0; q < 4; ++q) {
        float4 hv = *(const float4*)(hp + q * 4);
        float4 av = *(const float4*)(as_ + h * CDIM + q * 4);
        float4 dv = *(const float4*)(ad_ + h * CDIM + q * 4);
        s += hv.x * av.x + hv.y * av.y + hv.z * av.z + hv.w * av.w;
        d += hv.x * dv.x + hv.y * dv.y + hv.z * dv.z + hv.w * dv.w;
    }
    asrc[node * NHEAD + h] = s;
    adst[node * NHEAD + h] = d;
}

// one wave per dst node; single pass, no max-subtraction (alpha is O(1):
// exp never overflows; exp(a)/sum exp(a) == exp(a-m)/sum exp(a-m)).
// 4-way unrolled edge loop -> 4 independent gather chains in flight.
__global__ __launch_bounds__(256) void gat_aggregate(
    const float* __restrict__ hlin,     // [n,128]
    const float* __restrict__ asrc,     // [n,8]
    const float* __restrict__ adst,     // [n,8]
    const int2*  __restrict__ epack,    // [E] dst-sorted {src, bits(eattr)}
    const int*   __restrict__ eoff,     // [n+1]
    const float* __restrict__ kc,       // [8] this layer
    const float* __restrict__ bias,     // [128]
    const float* __restrict__ floop,    // [n] self-loop attr
    float* __restrict__ out,            // [n,128]
    int n, int use_loop) {
    int nid = (blockIdx.x * 256 + threadIdx.x) >> 6;
    if (nid >= n) return;
    const int lane = threadIdx.x & 63;
    const int h = lane >> 3;
    const int c0 = lane * 2;

    const float adst_h = adst[nid * NHEAD + h];
    const float k_h = kc[h];
    const int e0 = eoff[nid], e1 = eoff[nid + 1];

    float den = 0.f, acc0 = 0.f, acc1 = 0.f;

    // self-loop first so its gathers overlap the edge loop
    if (use_loop) {
        float a = asrc[nid * NHEAD + h] + adst_h + floop[nid] * k_h;
        a = (a > 0.f) ? a : 0.2f * a;
        float w = __expf(a);
        float2 hv = *(const float2*)(hlin + (long)nid * HCDIM + c0);
        den += w; acc0 += hv.x * w; acc1 += hv.y * w;
    }

    for (int base = e0; base < e1; base += 4) {
        int2 ep[4];
#pragma unroll
        for (int j = 0; j < 4; ++j) {
            int idx = base + j; idx = (idx < e1) ? idx : (e1 - 1);
            ep[j] = epack[idx];
        }
        float av[4]; float2 hv[4];
#pragma unroll
        for (int j = 0; j < 4; ++j) {
            av[j] = asrc[ep[j].x * NHEAD + h];
            hv[j] = *(const float2*)(hlin + (long)ep[j].x * HCDIM + c0);
        }
#pragma unroll
        for (int j = 0; j < 4; ++j) {
            float a = av[j] + adst_h + __int_as_float(ep[j].y) * k_h;
            a = (a > 0.f) ? a : 0.2f * a;
            float w = __expf(a);
            w = (base + j < e1) ? w : 0.f;
            den += w; acc0 += hv[j].x * w; acc1 += hv[j].y * w;
        }
    }

    float inv = 1.f / (den + 1e-16f);
    float o0 = fmaxf(acc0 * inv + bias[c0], 0.f);
    float o1 = fmaxf(acc1 * inv + bias[c0 + 1], 0.f);
    *(float2*)(out + (long)nid * HCDIM + c0) = make_float2(o0, o1);
}

// ---------------------------------------------------------------- pool + MLP

__global__ __launch_bounds__(128) void pool_kernel(const float* __restrict__ H,
                                                   const int* __restrict__ batch,
                                                   float* __restrict__ gsum, int n) {
    const int c = threadIdx.x;            // 0..127
    const int n0 = blockIdx.x * 128;
    if (n0 >= n) return;
    const int n1 = min(n0 + 128, n);
    float acc = 0.f;
    int cg = batch[n0];
    for (int i = n0; i < n1; ++i) {
        int g = batch[i];
        if (g != cg) {
            atomicAdd(&gsum[cg * HCDIM + c], acc);
            acc = 0.f;
            cg = g;
        }
        acc += H[(long)i * HCDIM + c];
    }
    atomicAdd(&gsum[cg * HCDIM + c], acc);
}

__global__ __launch_bounds__(64) void mlp_kernel(const float* __restrict__ gsum,
                                                 const int* __restrict__ gstart,
                                                 const float* __restrict__ fw1,
                                                 const float* __restrict__ fb1,
                                                 const float* __restrict__ fw2,
                                                 const float* __restrict__ fb2,
                                                 float* __restrict__ out) {
    const int g = blockIdx.x;
    const int j = threadIdx.x;            // 0..63
    __shared__ float emb[HCDIM];
    __shared__ float gh[64];
    int cnt = gstart[g + 1] - gstart[g];
    float invc = 1.f / fmaxf((float)cnt, 1.f);
    emb[j] = gsum[g * HCDIM + j] * invc;
    emb[j + 64] = gsum[g * HCDIM + 64 + j] * invc;
    __syncthreads();
    float a = fb1[j];
    for (int k = 0; k < HCDIM; ++k) a += emb[k] * fw1[k * 64 + j];
    gh[j] = fmaxf(a, 0.f);
    __syncthreads();
    if (j < 2) {
        float o = fb2[j];
        for (int k = 0; k < 64; ++k) o += gh[k] * fw2[k * 2 + j];
        out[g * 2 + j] = o;
    }
}

// ---------------------------------------------------------------- launcher

extern "C" void kernel_launch(void* const* d_in, const int* in_sizes, int n_in,
                              void* d_out, int out_size, void* d_ws, size_t ws_size,
                              hipStream_t stream) {
    const float* x     = (const float*)d_in[0];
    const int*   eidx  = (const int*)d_in[1];
    const float* eattr = (const float*)d_in[2];
    const int*   batch = (const int*)d_in[3];
    const float* w1  = (const float*)d_in[4];
    const float* as1 = (const float*)d_in[5];
    const float* ad1 = (const float*)d_in[6];
    const float* we1 = (const float*)d_in[7];
    const float* ae1 = (const float*)d_in[8];
    const float* b1  = (const float*)d_in[9];
    const float* w2  = (const float*)d_in[10];
    const float* as2 = (const float*)d_in[11];
    const float* ad2 = (const float*)d_in[12];
    const float* we2 = (const float*)d_in[13];
    const float* ae2 = (const float*)d_in[14];
    const float* b2  = (const float*)d_in[15];
    const float* w3  = (const float*)d_in[16];
    const float* as3 = (const float*)d_in[17];
    const float* ad3 = (const float*)d_in[18];
    const float* we3 = (const float*)d_in[19];
    const float* ae3 = (const float*)d_in[20];
    const float* b3  = (const float*)d_in[21];
    const float* fw1 = (const float*)d_in[22];
    const float* fb1 = (const float*)d_in[23];
    const float* fw2 = (const float*)d_in[24];
    const float* fb2 = (const float*)d_in[25];

    const int N = in_sizes[3];
    const int E = in_sizes[2];
    const int* src = eidx;
    const int* dst = eidx + E;

    // workspace carve
    char* p = (char*)d_ws;
    auto alloc = [&](size_t bytes) {
        void* r = (void*)p;
        p += (bytes + 255) & ~(size_t)255;
        return r;
    };
    float* A      = (float*)alloc((size_t)N * HCDIM * 4);
    float* B      = (float*)alloc((size_t)N * HCDIM * 4);
    float* asrc   = (float*)alloc((size_t)N * NHEAD * 4);
    float* adst   = (float*)alloc((size_t)N * NHEAD * 4);
    int*   deg    = (int*)alloc((size_t)N * 4);
    int*   eoff   = (int*)alloc((size_t)(N + 1) * 4);
    int*   cursor = (int*)alloc((size_t)N * 4);
    int2*  epack  = (int2*)alloc((size_t)E * 8);
    float* sume   = (float*)alloc((size_t)N * 4);
    float* floop  = (float*)alloc((size_t)N * 4);
    int*   bsum   = (int*)alloc(((size_t)(N + 255) / 256) * 4);
    float* kc     = (float*)alloc(24 * 4);
    int*   gstart = (int*)alloc((NGRAPH + 1) * 4);
    float* gsum   = (float*)alloc(NGRAPH * HCDIM * 4);

    const int NB = (N + 255) / 256;
    const int EB = (E + 255) / 256;
    const int WAVE_BLOCKS = (N * 64 + 255) / 256;   // one wave per node

    zero_kernel<<<NB, 256, 0, stream>>>(deg, sume, cursor, gsum, N);
    count_deg<<<EB, 256, 0, stream>>>(dst, eattr, deg, sume, E);
    block_sum<<<NB, 256, 0, stream>>>(deg, bsum, N);
    scan_bsums<<<1, 512, 0, stream>>>(bsum, NB);
    scan_final<<<NB, 256, 0, stream>>>(deg, bsum, eoff, N);
    scatter_edges<<<EB, 256, 0, stream>>>(src, dst, eattr, eoff, cursor, epack, E);
    compute_loop_attr<<<NB, 256, 0, stream>>>(deg, sume, floop, N);
    kcoef_kernel<<<1, 32, 0, stream>>>(we1, ae1, we2, ae2, we3, ae3, kc);
    graph_bounds<<<1, 128, 0, stream>>>(batch, gstart, N);

    // layer 1 (no self loops)
    lin4_128<<<(N * 64 + 255) / 256, 256, 0, stream>>>(x, w1, A, N);
    attn_coeff<<<(N * 8 + 255) / 256, 256, 0, stream>>>(A, as1, ad1, asrc, adst, N);
    gat_aggregate<<<WAVE_BLOCKS, 256, 0, stream>>>(A, asrc, adst, epack, eoff,
                                                   kc + 0, b1, floop, B, N, 0);
    // layer 2 (self loops, fill=mean)
    gemm_128x128<<<(N + 63) / 64, 256, 0, stream>>>(B, w2, A, N);
    attn_coeff<<<(N * 8 + 255) / 256, 256, 0, stream>>>(A, as2, ad2, asrc, adst, N);
    gat_aggregate<<<WAVE_BLOCKS, 256, 0, stream>>>(A, asrc, adst, epack, eoff,
                                                   kc + 8, b2, floop, B, N, 1);
    // layer 3
    gemm_128x128<<<(N + 63) / 64, 256, 0, stream>>>(B, w3, A, N);
    attn_coeff<<<(N * 8 + 255) / 256, 256, 0, stream>>>(A, as3, ad3, asrc, adst, N);
    gat_aggregate<<<WAVE_BLOCKS, 256, 0, stream>>>(A, asrc, adst, epack, eoff,
                                                   kc + 16, b3, floop, B, N, 1);

    // mean-pool + MLP head
    pool_kernel<<<(N + 127) / 128, 128, 0, stream>>>(B, batch, gsum, N);
    mlp_kernel<<<NGRAPH, 64, 0, stream>>>(gsum, gstart, fw1, fb1, fw2, fb2, (float*)d_out);
}

// Round 3
// 616.270 us; speedup vs baseline: 1.6004x; 1.0959x over previous
//
#include <hip/hip_runtime.h>
#include <hip/hip_bf16.h>
#include <math.h>

#define NHEAD 8
#define CDIM 16
#define HCDIM 128
#define NGRAPH 64

typedef __attribute__((ext_vector_type(8))) short short8;
typedef __attribute__((ext_vector_type(4))) float f32x4;

static __device__ __forceinline__ unsigned short f2bf(float f) {
    unsigned u = __float_as_uint(f);
    unsigned r = (u + 0x7FFF + ((u >> 16) & 1)) >> 16;   // rne
    return (unsigned short)r;
}
static __device__ __forceinline__ float bf2f(unsigned short s) {
    return __uint_as_float(((unsigned)s) << 16);
}

// ---------------------------------------------------------------- utilities

__global__ void zero_kernel(int* __restrict__ deg, float* __restrict__ sume,
                            int* __restrict__ cursor, float* __restrict__ gsum, int n) {
    int i = blockIdx.x * 256 + threadIdx.x;
    if (i < n) { deg[i] = 0; sume[i] = 0.f; cursor[i] = 0; }
    if (i < NGRAPH * HCDIM) gsum[i] = 0.f;
}

__global__ void count_deg(const int* __restrict__ dst, const float* __restrict__ eattr,
                          int* __restrict__ deg, float* __restrict__ sume, int E) {
    int e = blockIdx.x * 256 + threadIdx.x;
    if (e >= E) return;
    int d = dst[e];
    atomicAdd(&deg[d], 1);
    atomicAdd(&sume[d], eattr[e]);
}

__global__ void block_sum(const int* __restrict__ deg, int* __restrict__ bsum, int n) {
    __shared__ int s[256];
    int i = blockIdx.x * 256 + threadIdx.x;
    s[threadIdx.x] = (i < n) ? deg[i] : 0;
    __syncthreads();
    for (int off = 128; off > 0; off >>= 1) {
        if (threadIdx.x < off) s[threadIdx.x] += s[threadIdx.x + off];
        __syncthreads();
    }
    if (threadIdx.x == 0) bsum[blockIdx.x] = s[0];
}

__global__ void scan_bsums(int* __restrict__ bsum, int nb) {
    __shared__ int s[512];
    int t = threadIdx.x;
    int v = (t < nb) ? bsum[t] : 0;
    s[t] = v;
    __syncthreads();
    for (int off = 1; off < 512; off <<= 1) {
        int add = (t >= off) ? s[t - off] : 0;
        __syncthreads();
        s[t] += add;
        __syncthreads();
    }
    if (t < nb) bsum[t] = s[t] - v;   // exclusive base per block
}

__global__ void scan_final(const int* __restrict__ deg, const int* __restrict__ bbase,
                           int* __restrict__ eoff, int n) {
    __shared__ int s[256];
    int i = blockIdx.x * 256 + threadIdx.x;
    int v = (i < n) ? deg[i] : 0;
    s[threadIdx.x] = v;
    __syncthreads();
    for (int off = 1; off < 256; off <<= 1) {
        int add = (threadIdx.x >= off) ? s[threadIdx.x - off] : 0;
        __syncthreads();
        s[threadIdx.x] += add;
        __syncthreads();
    }
    if (i < n) eoff[i + 1] = bbase[blockIdx.x] + s[threadIdx.x];
    if (i == 0) eoff[0] = 0;
}

// writes dst-sorted packed edges: epack[p] = {src, bits(eattr)}
__global__ void scatter_edges(const int* __restrict__ src, const int* __restrict__ dst,
                              const float* __restrict__ eattr,
                              const int* __restrict__ eoff,
                              int* __restrict__ cursor, int2* __restrict__ epack, int E) {
    int e = blockIdx.x * 256 + threadIdx.x;
    if (e >= E) return;
    int d = dst[e];
    int p = eoff[d] + atomicAdd(&cursor[d], 1);
    epack[p] = make_int2(src[e], __float_as_int(eattr[e]));
}

__global__ void compute_loop_attr(const int* __restrict__ deg, const float* __restrict__ sume,
                                  float* __restrict__ floop, int n) {
    int i = blockIdx.x * 256 + threadIdx.x;
    if (i < n) floop[i] = sume[i] / fmaxf((float)deg[i], 1.f);
}

__global__ void kcoef_kernel(const float* __restrict__ we1, const float* __restrict__ ae1,
                             const float* __restrict__ we2, const float* __restrict__ ae2,
                             const float* __restrict__ we3, const float* __restrict__ ae3,
                             float* __restrict__ kc) {
    int t = threadIdx.x;
    if (t >= 24) return;
    int l = t >> 3, h = t & 7;
    const float* we = (l == 0) ? we1 : ((l == 1) ? we2 : we3);
    const float* ae = (l == 0) ? ae1 : ((l == 1) ? ae2 : ae3);
    float s = 0.f;
    for (int c = 0; c < CDIM; ++c) s += we[h * CDIM + c] * ae[h * CDIM + c];
    kc[t] = s;
}

__global__ void graph_bounds(const int* __restrict__ batch, int* __restrict__ gstart, int n) {
    int g = threadIdx.x;
    if (g > NGRAPH) return;
    int lo = 0, hi = n;
    while (lo < hi) {
        int mid = (lo + hi) >> 1;
        if (batch[mid] < g) lo = mid + 1; else hi = mid;
    }
    gstart[g] = lo;
}

// split w2/w3 into transposed bf16 hi/lo: Wt[n][k] = split(W[k][n])
__global__ void split_weights(const float* __restrict__ w2, const float* __restrict__ w3,
                              unsigned short* __restrict__ wt2h, unsigned short* __restrict__ wt2l,
                              unsigned short* __restrict__ wt3h, unsigned short* __restrict__ wt3l) {
    int t = blockIdx.x * 256 + threadIdx.x;
    if (t >= HCDIM * HCDIM) return;
    int k = t >> 7, nn = t & 127;
    float v = w2[t];
    unsigned short h = f2bf(v);
    wt2h[nn * HCDIM + k] = h;
    wt2l[nn * HCDIM + k] = f2bf(v - bf2f(h));
    v = w3[t];
    h = f2bf(v);
    wt3h[nn * HCDIM + k] = h;
    wt3l[nn * HCDIM + k] = f2bf(v - bf2f(h));
}

// ---------------------------------------------------------------- dense lins

// layer 1: [n,4] @ [4,128]
__global__ __launch_bounds__(256) void lin4_128(const float* __restrict__ X,
                                                const float* __restrict__ W,
                                                float* __restrict__ Y, int n) {
    int gid = blockIdx.x * 256 + threadIdx.x;
    int node = gid >> 6;
    if (node >= n) return;
    int lane = gid & 63;
    int c0 = lane * 2;
    float4 xv = *(const float4*)(X + (long)node * 4);
    float a0 = xv.x * W[c0]       + xv.y * W[128 + c0]     + xv.z * W[256 + c0]     + xv.w * W[384 + c0];
    float a1 = xv.x * W[c0 + 1]   + xv.y * W[128 + c0 + 1] + xv.z * W[256 + c0 + 1] + xv.w * W[384 + c0 + 1];
    *(float2*)(Y + (long)node * HCDIM + c0) = make_float2(a0, a1);
}

// layers 2/3: [n,128] @ [128,128] via split-bf16 MFMA.
// C = Ah*Bh + Al*Bh + Ah*Bl  (lo*lo dropped, ~2^-18 rel err).
// block = 4 waves, wave = 2 row-groups of 16 -> 128 rows/block. No LDS.
__global__ __launch_bounds__(256) void gemm_mfma(const unsigned short* __restrict__ Ahi,
                                                 const unsigned short* __restrict__ Alo,
                                                 const unsigned short* __restrict__ Wth,
                                                 const unsigned short* __restrict__ Wtl,
                                                 float* __restrict__ Y, int n) {
    const int wave = threadIdx.x >> 6;
    const int lane = threadIdx.x & 63;
    const int quad = lane >> 4;
    const int l16  = lane & 15;
    const int rowbase = (blockIdx.x * 8 + wave * 2) * 16;

    f32x4 acc[2][8];
#pragma unroll
    for (int r = 0; r < 2; ++r)
#pragma unroll
        for (int t = 0; t < 8; ++t) acc[r][t] = (f32x4){0.f, 0.f, 0.f, 0.f};

#pragma unroll
    for (int kb = 0; kb < HCDIM; kb += 32) {
        short8 ah[2], al[2];
#pragma unroll
        for (int r = 0; r < 2; ++r) {
            int row = rowbase + r * 16 + l16;
            row = (row < n) ? row : (n - 1);
            const long off = (long)row * HCDIM + kb + quad * 8;
            ah[r] = *(const short8*)(Ahi + off);
            al[r] = *(const short8*)(Alo + off);
        }
#pragma unroll
        for (int nt = 0; nt < 8; ++nt) {
            const long woff = (long)(nt * 16 + l16) * HCDIM + kb + quad * 8;
            short8 bh = *(const short8*)(Wth + woff);
            short8 bl = *(const short8*)(Wtl + woff);
#pragma unroll
            for (int r = 0; r < 2; ++r) {
                acc[r][nt] = __builtin_amdgcn_mfma_f32_16x16x32_bf16(ah[r], bh, acc[r][nt], 0, 0, 0);
                acc[r][nt] = __builtin_amdgcn_mfma_f32_16x16x32_bf16(al[r], bh, acc[r][nt], 0, 0, 0);
                acc[r][nt] = __builtin_amdgcn_mfma_f32_16x16x32_bf16(ah[r], bl, acc[r][nt], 0, 0, 0);
            }
        }
    }

    // C/D layout: col = l16, row_local = quad*4 + reg
#pragma unroll
    for (int r = 0; r < 2; ++r) {
#pragma unroll
        for (int reg = 0; reg < 4; ++reg) {
            int row = rowbase + r * 16 + quad * 4 + reg;
            if (row < n) {
                float* yp = Y + (long)row * HCDIM + l16;
#pragma unroll
                for (int nt = 0; nt < 8; ++nt) yp[nt * 16] = acc[r][nt][reg];
            }
        }
    }
}

// ---------------------------------------------------------------- attention

__global__ __launch_bounds__(256) void attn_coeff(const float* __restrict__ H,
                                                  const float* __restrict__ as_,
                                                  const float* __restrict__ ad_,
                                                  float* __restrict__ asrc,
                                                  float* __restrict__ adst, int n) {
    int gid = blockIdx.x * 256 + threadIdx.x;
    int node = gid >> 3;
    if (node >= n) return;
    int h = gid & 7;
    const float* hp = H + (long)node * HCDIM + h * CDIM;
    float s = 0.f, d = 0.f;
#pragma unroll
    for (int q = 0; q < 4; ++q) {
        float4 hv = *(const float4*)(hp + q * 4);
        float4 av = *(const float4*)(as_ + h * CDIM + q * 4);
        float4 dv = *(const float4*)(ad_ + h * CDIM + q * 4);
        s += hv.x * av.x + hv.y * av.y + hv.z * av.z + hv.w * av.w;
        d += hv.x * dv.x + hv.y * dv.y + hv.z * dv.z + hv.w * dv.w;
    }
    asrc[node * NHEAD + h] = s;
    adst[node * NHEAD + h] = d;
}

// one wave per dst node; single pass, no max-subtraction (alpha is O(1)).
// 4-way unrolled edge loop -> 4 independent gather chains in flight.
// split_out=1: emit bf16 hi/lo pair (feeds gemm_mfma); else fp32.
__global__ __launch_bounds__(256) void gat_aggregate(
    const float* __restrict__ hlin,     // [n,128]
    const float* __restrict__ asrc,     // [n,8]
    const float* __restrict__ adst,     // [n,8]
    const int2*  __restrict__ epack,    // [E] dst-sorted {src, bits(eattr)}
    const int*   __restrict__ eoff,     // [n+1]
    const float* __restrict__ kc,       // [8] this layer
    const float* __restrict__ bias,     // [128]
    const float* __restrict__ floop,    // [n] self-loop attr
    float* __restrict__ outf,           // [n,128] (split_out=0)
    unsigned short* __restrict__ outhi, // [n,128] (split_out=1)
    unsigned short* __restrict__ outlo, // [n,128]
    int n, int use_loop, int split_out) {
    int nid = (blockIdx.x * 256 + threadIdx.x) >> 6;
    if (nid >= n) return;
    const int lane = threadIdx.x & 63;
    const int h = lane >> 3;
    const int c0 = lane * 2;

    const float adst_h = adst[nid * NHEAD + h];
    const float k_h = kc[h];
    const int e0 = eoff[nid], e1 = eoff[nid + 1];

    float den = 0.f, acc0 = 0.f, acc1 = 0.f;

    if (use_loop) {
        float a = asrc[nid * NHEAD + h] + adst_h + floop[nid] * k_h;
        a = (a > 0.f) ? a : 0.2f * a;
        float w = __expf(a);
        float2 hv = *(const float2*)(hlin + (long)nid * HCDIM + c0);
        den += w; acc0 += hv.x * w; acc1 += hv.y * w;
    }

    for (int base = e0; base < e1; base += 4) {
        int2 ep[4];
#pragma unroll
        for (int j = 0; j < 4; ++j) {
            int idx = base + j; idx = (idx < e1) ? idx : (e1 - 1);
            ep[j] = epack[idx];
        }
        float av[4]; float2 hv[4];
#pragma unroll
        for (int j = 0; j < 4; ++j) {
            av[j] = asrc[ep[j].x * NHEAD + h];
            hv[j] = *(const float2*)(hlin + (long)ep[j].x * HCDIM + c0);
        }
#pragma unroll
        for (int j = 0; j < 4; ++j) {
            float a = av[j] + adst_h + __int_as_float(ep[j].y) * k_h;
            a = (a > 0.f) ? a : 0.2f * a;
            float w = __expf(a);
            w = (base + j < e1) ? w : 0.f;
            den += w; acc0 += hv[j].x * w; acc1 += hv[j].y * w;
        }
    }

    float inv = 1.f / (den + 1e-16f);
    float o0 = fmaxf(acc0 * inv + bias[c0], 0.f);
    float o1 = fmaxf(acc1 * inv + bias[c0 + 1], 0.f);
    if (split_out) {
        unsigned short h0 = f2bf(o0), h1 = f2bf(o1);
        unsigned short l0 = f2bf(o0 - bf2f(h0)), l1 = f2bf(o1 - bf2f(h1));
        *(ushort2*)(outhi + (long)nid * HCDIM + c0) = make_ushort2(h0, h1);
        *(ushort2*)(outlo + (long)nid * HCDIM + c0) = make_ushort2(l0, l1);
    } else {
        *(float2*)(outf + (long)nid * HCDIM + c0) = make_float2(o0, o1);
    }
}

// ---------------------------------------------------------------- pool + MLP

__global__ __launch_bounds__(128) void pool_kernel(const float* __restrict__ H,
                                                   const int* __restrict__ batch,
                                                   float* __restrict__ gsum, int n) {
    const int c = threadIdx.x;            // 0..127
    const int n0 = blockIdx.x * 128;
    if (n0 >= n) return;
    const int n1 = min(n0 + 128, n);
    float acc = 0.f;
    int cg = batch[n0];
    for (int i = n0; i < n1; ++i) {
        int g = batch[i];
        if (g != cg) {
            atomicAdd(&gsum[cg * HCDIM + c], acc);
            acc = 0.f;
            cg = g;
        }
        acc += H[(long)i * HCDIM + c];
    }
    atomicAdd(&gsum[cg * HCDIM + c], acc);
}

__global__ __launch_bounds__(64) void mlp_kernel(const float* __restrict__ gsum,
                                                 const int* __restrict__ gstart,
                                                 const float* __restrict__ fw1,
                                                 const float* __restrict__ fb1,
                                                 const float* __restrict__ fw2,
                                                 const float* __restrict__ fb2,
                                                 float* __restrict__ out) {
    const int g = blockIdx.x;
    const int j = threadIdx.x;            // 0..63
    __shared__ float emb[HCDIM];
    __shared__ float gh[64];
    int cnt = gstart[g + 1] - gstart[g];
    float invc = 1.f / fmaxf((float)cnt, 1.f);
    emb[j] = gsum[g * HCDIM + j] * invc;
    emb[j + 64] = gsum[g * HCDIM + 64 + j] * invc;
    __syncthreads();
    float a = fb1[j];
    for (int k = 0; k < HCDIM; ++k) a += emb[k] * fw1[k * 64 + j];
    gh[j] = fmaxf(a, 0.f);
    __syncthreads();
    if (j < 2) {
        float o = fb2[j];
        for (int k = 0; k < 64; ++k) o += gh[k] * fw2[k * 2 + j];
        out[g * 2 + j] = o;
    }
}

// ---------------------------------------------------------------- launcher

extern "C" void kernel_launch(void* const* d_in, const int* in_sizes, int n_in,
                              void* d_out, int out_size, void* d_ws, size_t ws_size,
                              hipStream_t stream) {
    const float* x     = (const float*)d_in[0];
    const int*   eidx  = (const int*)d_in[1];
    const float* eattr = (const float*)d_in[2];
    const int*   batch = (const int*)d_in[3];
    const float* w1  = (const float*)d_in[4];
    const float* as1 = (const float*)d_in[5];
    const float* ad1 = (const float*)d_in[6];
    const float* we1 = (const float*)d_in[7];
    const float* ae1 = (const float*)d_in[8];
    const float* b1  = (const float*)d_in[9];
    const float* w2  = (const float*)d_in[10];
    const float* as2 = (const float*)d_in[11];
    const float* ad2 = (const float*)d_in[12];
    const float* we2 = (const float*)d_in[13];
    const float* ae2 = (const float*)d_in[14];
    const float* b2  = (const float*)d_in[15];
    const float* w3  = (const float*)d_in[16];
    const float* as3 = (const float*)d_in[17];
    const float* ad3 = (const float*)d_in[18];
    const float* we3 = (const float*)d_in[19];
    const float* ae3 = (const float*)d_in[20];
    const float* b3  = (const float*)d_in[21];
    const float* fw1 = (const float*)d_in[22];
    const float* fb1 = (const float*)d_in[23];
    const float* fw2 = (const float*)d_in[24];
    const float* fb2 = (const float*)d_in[25];

    const int N = in_sizes[3];
    const int E = in_sizes[2];
    const int* src = eidx;
    const int* dst = eidx + E;

    // workspace carve
    char* p = (char*)d_ws;
    auto alloc = [&](size_t bytes) {
        void* r = (void*)p;
        p += (bytes + 255) & ~(size_t)255;
        return r;
    };
    float* A      = (float*)alloc((size_t)N * HCDIM * 4);
    // B region: bf16 hi/lo pair (layers 1-2) ALIASED with fp32 (layer 3 -> pool).
    // hi/lo are dead by the time agg3 overwrites with fp32.
    char*  Bbuf   = (char*)alloc((size_t)N * HCDIM * 4);
    unsigned short* Bhi = (unsigned short*)Bbuf;
    unsigned short* Blo = Bhi + (size_t)N * HCDIM;
    float* Bf32   = (float*)Bbuf;
    float* asrc   = (float*)alloc((size_t)N * NHEAD * 4);
    float* adst   = (float*)alloc((size_t)N * NHEAD * 4);
    int*   deg    = (int*)alloc((size_t)N * 4);
    int*   eoff   = (int*)alloc((size_t)(N + 1) * 4);
    int*   cursor = (int*)alloc((size_t)N * 4);
    int2*  epack  = (int2*)alloc((size_t)E * 8);
    float* sume   = (float*)alloc((size_t)N * 4);
    float* floop  = (float*)alloc((size_t)N * 4);
    int*   bsum   = (int*)alloc(((size_t)(N + 255) / 256) * 4);
    float* kc     = (float*)alloc(24 * 4);
    int*   gstart = (int*)alloc((NGRAPH + 1) * 4);
    float* gsum   = (float*)alloc(NGRAPH * HCDIM * 4);
    unsigned short* wt2h = (unsigned short*)alloc(HCDIM * HCDIM * 2);
    unsigned short* wt2l = (unsigned short*)alloc(HCDIM * HCDIM * 2);
    unsigned short* wt3h = (unsigned short*)alloc(HCDIM * HCDIM * 2);
    unsigned short* wt3l = (unsigned short*)alloc(HCDIM * HCDIM * 2);

    const int NB = (N + 255) / 256;
    const int EB = (E + 255) / 256;
    const int WAVE_BLOCKS = (N * 64 + 255) / 256;   // one wave per node
    const int GEMM_BLOCKS = (N + 127) / 128;        // 128 rows per block

    zero_kernel<<<NB, 256, 0, stream>>>(deg, sume, cursor, gsum, N);
    count_deg<<<EB, 256, 0, stream>>>(dst, eattr, deg, sume, E);
    block_sum<<<NB, 256, 0, stream>>>(deg, bsum, N);
    scan_bsums<<<1, 512, 0, stream>>>(bsum, NB);
    scan_final<<<NB, 256, 0, stream>>>(deg, bsum, eoff, N);
    scatter_edges<<<EB, 256, 0, stream>>>(src, dst, eattr, eoff, cursor, epack, E);
    compute_loop_attr<<<NB, 256, 0, stream>>>(deg, sume, floop, N);
    kcoef_kernel<<<1, 32, 0, stream>>>(we1, ae1, we2, ae2, we3, ae3, kc);
    graph_bounds<<<1, 128, 0, stream>>>(batch, gstart, N);
    split_weights<<<(HCDIM * HCDIM + 255) / 256, 256, 0, stream>>>(w2, w3, wt2h, wt2l, wt3h, wt3l);

    // layer 1 (no self loops): out -> bf16 hi/lo
    lin4_128<<<(N * 64 + 255) / 256, 256, 0, stream>>>(x, w1, A, N);
    attn_coeff<<<(N * 8 + 255) / 256, 256, 0, stream>>>(A, as1, ad1, asrc, adst, N);
    gat_aggregate<<<WAVE_BLOCKS, 256, 0, stream>>>(A, asrc, adst, epack, eoff,
                                                   kc + 0, b1, floop, Bf32, Bhi, Blo, N, 0, 1);
    // layer 2 (self loops, fill=mean): out -> bf16 hi/lo
    gemm_mfma<<<GEMM_BLOCKS, 256, 0, stream>>>(Bhi, Blo, wt2h, wt2l, A, N);
    attn_coeff<<<(N * 8 + 255) / 256, 256, 0, stream>>>(A, as2, ad2, asrc, adst, N);
    gat_aggregate<<<WAVE_BLOCKS, 256, 0, stream>>>(A, asrc, adst, epack, eoff,
                                                   kc + 8, b2, floop, Bf32, Bhi, Blo, N, 1, 1);
    // layer 3: out -> fp32 (pool consumes)
    gemm_mfma<<<GEMM_BLOCKS, 256, 0, stream>>>(Bhi, Blo, wt3h, wt3l, A, N);
    attn_coeff<<<(N * 8 + 255) / 256, 256, 0, stream>>>(A, as3, ad3, asrc, adst, N);
    gat_aggregate<<<WAVE_BLOCKS, 256, 0, stream>>>(A, asrc, adst, epack, eoff,
                                                   kc + 16, b3, floop, Bf32, Bhi, Blo, N, 1, 0);

    // mean-pool + MLP head
    pool_kernel<<<(N + 127) / 128, 128, 0, stream>>>(Bf32, batch, gsum, N);
    mlp_kernel<<<NGRAPH, 64, 0, stream>>>(gsum, gstart, fw1, fb1, fw2, fb2, (float*)d_out);
}

// Round 4
// 588.813 us; speedup vs baseline: 1.6750x; 1.0466x over previous
//
#include <hip/hip_runtime.h>
#include <hip/hip_bf16.h>
#include <math.h>

#define NHEAD 8
#define CDIM 16
#define HCDIM 128
#define NGRAPH 64

typedef __attribute__((ext_vector_type(8))) short short8;
typedef __attribute__((ext_vector_type(4))) float f32x4;

static __device__ __forceinline__ unsigned short f2bf(float f) {
    unsigned u = __float_as_uint(f);
    unsigned r = (u + 0x7FFF + ((u >> 16) & 1)) >> 16;   // rne
    return (unsigned short)r;
}
static __device__ __forceinline__ float bf2f(unsigned short s) {
    return __uint_as_float(((unsigned)s) << 16);
}

// ---------------------------------------------------------------- setup

// merged: zero deg/sume/cursor/gsum + split w2/w3 + kcoef + graph_bounds
__global__ void setup0(int* __restrict__ deg, float* __restrict__ sume,
                       int* __restrict__ cursor, float* __restrict__ gsum,
                       const float* __restrict__ w2, const float* __restrict__ w3,
                       unsigned short* __restrict__ wt2h, unsigned short* __restrict__ wt2l,
                       unsigned short* __restrict__ wt3h, unsigned short* __restrict__ wt3l,
                       const float* __restrict__ we1, const float* __restrict__ ae1,
                       const float* __restrict__ we2, const float* __restrict__ ae2,
                       const float* __restrict__ we3, const float* __restrict__ ae3,
                       float* __restrict__ kc,
                       const int* __restrict__ batch, int* __restrict__ gstart, int n) {
    int i = blockIdx.x * 256 + threadIdx.x;
    if (i < n) { deg[i] = 0; sume[i] = 0.f; cursor[i] = 0; }
    if (i < NGRAPH * HCDIM) gsum[i] = 0.f;
    if (i < HCDIM * HCDIM) {
        int k = i >> 7, nn = i & 127;
        float v = w2[i];
        unsigned short h = f2bf(v);
        wt2h[nn * HCDIM + k] = h;
        wt2l[nn * HCDIM + k] = f2bf(v - bf2f(h));
        v = w3[i];
        h = f2bf(v);
        wt3h[nn * HCDIM + k] = h;
        wt3l[nn * HCDIM + k] = f2bf(v - bf2f(h));
    }
    if (i < 24) {
        int l = i >> 3, h = i & 7;
        const float* we = (l == 0) ? we1 : ((l == 1) ? we2 : we3);
        const float* ae = (l == 0) ? ae1 : ((l == 1) ? ae2 : ae3);
        float s = 0.f;
        for (int c = 0; c < CDIM; ++c) s += we[h * CDIM + c] * ae[h * CDIM + c];
        kc[i] = s;
    }
    if (i >= 32 && i <= 32 + NGRAPH) {   // graph bounds in a separate lane range
        int g = i - 32;
        int lo = 0, hi = n;
        while (lo < hi) {
            int mid = (lo + hi) >> 1;
            if (batch[mid] < g) lo = mid + 1; else hi = mid;
        }
        gstart[g] = lo;
    }
}

__global__ void count_deg(const int* __restrict__ dst, const float* __restrict__ eattr,
                          int* __restrict__ deg, float* __restrict__ sume, int E) {
    int e = blockIdx.x * 256 + threadIdx.x;
    if (e >= E) return;
    int d = dst[e];
    atomicAdd(&deg[d], 1);
    atomicAdd(&sume[d], eattr[e]);
}

__global__ void block_sum(const int* __restrict__ deg, int* __restrict__ bsum, int n) {
    __shared__ int s[256];
    int i = blockIdx.x * 256 + threadIdx.x;
    s[threadIdx.x] = (i < n) ? deg[i] : 0;
    __syncthreads();
    for (int off = 128; off > 0; off >>= 1) {
        if (threadIdx.x < off) s[threadIdx.x] += s[threadIdx.x + off];
        __syncthreads();
    }
    if (threadIdx.x == 0) bsum[blockIdx.x] = s[0];
}

__global__ void scan_bsums(int* __restrict__ bsum, int nb) {
    __shared__ int s[512];
    int t = threadIdx.x;
    int v = (t < nb) ? bsum[t] : 0;
    s[t] = v;
    __syncthreads();
    for (int off = 1; off < 512; off <<= 1) {
        int add = (t >= off) ? s[t - off] : 0;
        __syncthreads();
        s[t] += add;
        __syncthreads();
    }
    if (t < nb) bsum[t] = s[t] - v;   // exclusive base per block
}

// + fused floop computation (self-loop attr = mean of incoming eattr)
__global__ void scan_final(const int* __restrict__ deg, const int* __restrict__ bbase,
                           const float* __restrict__ sume,
                           int* __restrict__ eoff, float* __restrict__ floop, int n) {
    __shared__ int s[256];
    int i = blockIdx.x * 256 + threadIdx.x;
    int v = (i < n) ? deg[i] : 0;
    s[threadIdx.x] = v;
    __syncthreads();
    for (int off = 1; off < 256; off <<= 1) {
        int add = (threadIdx.x >= off) ? s[threadIdx.x - off] : 0;
        __syncthreads();
        s[threadIdx.x] += add;
        __syncthreads();
    }
    if (i < n) {
        eoff[i + 1] = bbase[blockIdx.x] + s[threadIdx.x];
        floop[i] = sume[i] / fmaxf((float)v, 1.f);
    }
    if (i == 0) eoff[0] = 0;
}

// writes dst-sorted packed edges: epack[p] = {src, bits(eattr)}
__global__ void scatter_edges(const int* __restrict__ src, const int* __restrict__ dst,
                              const float* __restrict__ eattr,
                              const int* __restrict__ eoff,
                              int* __restrict__ cursor, int2* __restrict__ epack, int E) {
    int e = blockIdx.x * 256 + threadIdx.x;
    if (e >= E) return;
    int d = dst[e];
    int p = eoff[d] + atomicAdd(&cursor[d], 1);
    epack[p] = make_int2(src[e], __float_as_int(eattr[e]));
}

// ---------------------------------------------------------------- dense lins

// layer 1: [n,4] @ [4,128], fused with attn-coeff (8-lane shuffle reduction)
__global__ __launch_bounds__(256) void lin4_attn(const float* __restrict__ X,
                                                 const float* __restrict__ W,
                                                 const float* __restrict__ as_,
                                                 const float* __restrict__ ad_,
                                                 float* __restrict__ Y,
                                                 float* __restrict__ asrc,
                                                 float* __restrict__ adst, int n) {
    int gid = blockIdx.x * 256 + threadIdx.x;
    int node = gid >> 6;
    if (node >= n) return;
    int lane = threadIdx.x & 63;
    int c0 = lane * 2;
    float4 xv = *(const float4*)(X + (long)node * 4);
    float a0 = xv.x * W[c0]       + xv.y * W[128 + c0]     + xv.z * W[256 + c0]     + xv.w * W[384 + c0];
    float a1 = xv.x * W[c0 + 1]   + xv.y * W[128 + c0 + 1] + xv.z * W[256 + c0 + 1] + xv.w * W[384 + c0 + 1];
    *(float2*)(Y + (long)node * HCDIM + c0) = make_float2(a0, a1);

    int h = lane >> 3;
    int cc = c0 & 15;
    float ps = a0 * as_[h * CDIM + cc] + a1 * as_[h * CDIM + cc + 1];
    float pd = a0 * ad_[h * CDIM + cc] + a1 * ad_[h * CDIM + cc + 1];
    ps += __shfl_xor(ps, 1); ps += __shfl_xor(ps, 2); ps += __shfl_xor(ps, 4);
    pd += __shfl_xor(pd, 1); pd += __shfl_xor(pd, 2); pd += __shfl_xor(pd, 4);
    if ((lane & 7) == 0) {
        asrc[node * NHEAD + h] = ps;
        adst[node * NHEAD + h] = pd;
    }
}

// layers 2/3: [n,128] @ [128,128] via split-bf16 MFMA.
__global__ __launch_bounds__(256) void gemm_mfma(const unsigned short* __restrict__ Ahi,
                                                 const unsigned short* __restrict__ Alo,
                                                 const unsigned short* __restrict__ Wth,
                                                 const unsigned short* __restrict__ Wtl,
                                                 float* __restrict__ Y, int n) {
    const int wave = threadIdx.x >> 6;
    const int lane = threadIdx.x & 63;
    const int quad = lane >> 4;
    const int l16  = lane & 15;
    const int rowbase = (blockIdx.x * 8 + wave * 2) * 16;

    f32x4 acc[2][8];
#pragma unroll
    for (int r = 0; r < 2; ++r)
#pragma unroll
        for (int t = 0; t < 8; ++t) acc[r][t] = (f32x4){0.f, 0.f, 0.f, 0.f};

#pragma unroll
    for (int kb = 0; kb < HCDIM; kb += 32) {
        short8 ah[2], al[2];
#pragma unroll
        for (int r = 0; r < 2; ++r) {
            int row = rowbase + r * 16 + l16;
            row = (row < n) ? row : (n - 1);
            const long off = (long)row * HCDIM + kb + quad * 8;
            ah[r] = *(const short8*)(Ahi + off);
            al[r] = *(const short8*)(Alo + off);
        }
#pragma unroll
        for (int nt = 0; nt < 8; ++nt) {
            const long woff = (long)(nt * 16 + l16) * HCDIM + kb + quad * 8;
            short8 bh = *(const short8*)(Wth + woff);
            short8 bl = *(const short8*)(Wtl + woff);
#pragma unroll
            for (int r = 0; r < 2; ++r) {
                acc[r][nt] = __builtin_amdgcn_mfma_f32_16x16x32_bf16(ah[r], bh, acc[r][nt], 0, 0, 0);
                acc[r][nt] = __builtin_amdgcn_mfma_f32_16x16x32_bf16(al[r], bh, acc[r][nt], 0, 0, 0);
                acc[r][nt] = __builtin_amdgcn_mfma_f32_16x16x32_bf16(ah[r], bl, acc[r][nt], 0, 0, 0);
            }
        }
    }

    // C/D layout: col = l16, row_local = quad*4 + reg
#pragma unroll
    for (int r = 0; r < 2; ++r) {
#pragma unroll
        for (int reg = 0; reg < 4; ++reg) {
            int row = rowbase + r * 16 + quad * 4 + reg;
            if (row < n) {
                float* yp = Y + (long)row * HCDIM + l16;
#pragma unroll
                for (int nt = 0; nt < 8; ++nt) yp[nt * 16] = acc[r][nt][reg];
            }
        }
    }
}

// ---------------------------------------------------------------- attention

__global__ __launch_bounds__(256) void attn_coeff(const float* __restrict__ H,
                                                  const float* __restrict__ as_,
                                                  const float* __restrict__ ad_,
                                                  float* __restrict__ asrc,
                                                  float* __restrict__ adst, int n) {
    int gid = blockIdx.x * 256 + threadIdx.x;
    int node = gid >> 3;
    if (node >= n) return;
    int h = gid & 7;
    const float* hp = H + (long)node * HCDIM + h * CDIM;
    float s = 0.f, d = 0.f;
#pragma unroll
    for (int q = 0; q < 4; ++q) {
        float4 hv = *(const float4*)(hp + q * 4);
        float4 av = *(const float4*)(as_ + h * CDIM + q * 4);
        float4 dv = *(const float4*)(ad_ + h * CDIM + q * 4);
        s += hv.x * av.x + hv.y * av.y + hv.z * av.z + hv.w * av.w;
        d += hv.x * dv.x + hv.y * dv.y + hv.z * dv.z + hv.w * dv.w;
    }
    asrc[node * NHEAD + h] = s;
    adst[node * NHEAD + h] = d;
}

// TWO nodes per wave (32 lanes x float4 channels each); single pass,
// no max-subtraction (alpha is O(1): exp(a)/sum exp(a) identical).
// 4-way unrolled edge loop per half-wave -> 4 gather chains in flight.
__global__ __launch_bounds__(256) void gat_aggregate(
    const float* __restrict__ hlin,     // [n,128]
    const float* __restrict__ asrc,     // [n,8]
    const float* __restrict__ adst,     // [n,8]
    const int2*  __restrict__ epack,    // [E] dst-sorted {src, bits(eattr)}
    const int*   __restrict__ eoff,     // [n+1]
    const float* __restrict__ kc,       // [8] this layer
    const float* __restrict__ bias,     // [128]
    const float* __restrict__ floop,    // [n] self-loop attr
    float* __restrict__ outf,           // [n,128] (split_out=0)
    unsigned short* __restrict__ outhi, // [n,128] (split_out=1)
    unsigned short* __restrict__ outlo, // [n,128]
    int n, int use_loop, int split_out) {
    const int lane = threadIdx.x & 63;
    const int hl = lane & 31;
    int nid = ((blockIdx.x * 256 + threadIdx.x) >> 6) * 2 + (lane >> 5);
    if (nid >= n) return;
    const int h = hl >> 2;            // 4 lanes per head
    const int c0 = hl * 4;            // 4 contiguous channels per lane

    const float adst_h = adst[nid * NHEAD + h];
    const float k_h = kc[h];
    const int e0 = eoff[nid], e1 = eoff[nid + 1];

    float den = 0.f;
    float ax = 0.f, ay = 0.f, az = 0.f, aw = 0.f;

    if (use_loop) {
        float a = asrc[nid * NHEAD + h] + adst_h + floop[nid] * k_h;
        a = (a > 0.f) ? a : 0.2f * a;
        float w = __expf(a);
        float4 hv = *(const float4*)(hlin + (long)nid * HCDIM + c0);
        den = w; ax = hv.x * w; ay = hv.y * w; az = hv.z * w; aw = hv.w * w;
    }

    for (int base = e0; base < e1; base += 4) {
        int2 ep[4];
#pragma unroll
        for (int j = 0; j < 4; ++j) {
            int idx = base + j; idx = (idx < e1) ? idx : (e1 - 1);
            ep[j] = epack[idx];
        }
        float av[4]; float4 hv[4];
#pragma unroll
        for (int j = 0; j < 4; ++j) {
            av[j] = asrc[ep[j].x * NHEAD + h];
            hv[j] = *(const float4*)(hlin + (long)ep[j].x * HCDIM + c0);
        }
#pragma unroll
        for (int j = 0; j < 4; ++j) {
            float a = av[j] + adst_h + __int_as_float(ep[j].y) * k_h;
            a = (a > 0.f) ? a : 0.2f * a;
            float w = __expf(a);
            w = (base + j < e1) ? w : 0.f;
            den += w;
            ax += hv[j].x * w; ay += hv[j].y * w; az += hv[j].z * w; aw += hv[j].w * w;
        }
    }

    float inv = 1.f / (den + 1e-16f);
    float4 bv = *(const float4*)(bias + c0);
    float o0 = fmaxf(ax * inv + bv.x, 0.f);
    float o1 = fmaxf(ay * inv + bv.y, 0.f);
    float o2 = fmaxf(az * inv + bv.z, 0.f);
    float o3 = fmaxf(aw * inv + bv.w, 0.f);
    if (split_out) {
        unsigned short h0 = f2bf(o0), h1 = f2bf(o1), h2 = f2bf(o2), h3 = f2bf(o3);
        ushort4 hi = make_ushort4(h0, h1, h2, h3);
        ushort4 lo = make_ushort4(f2bf(o0 - bf2f(h0)), f2bf(o1 - bf2f(h1)),
                                  f2bf(o2 - bf2f(h2)), f2bf(o3 - bf2f(h3)));
        *(ushort4*)(outhi + (long)nid * HCDIM + c0) = hi;
        *(ushort4*)(outlo + (long)nid * HCDIM + c0) = lo;
    } else {
        *(float4*)(outf + (long)nid * HCDIM + c0) = make_float4(o0, o1, o2, o3);
    }
}

// ---------------------------------------------------------------- pool + MLP

__global__ __launch_bounds__(128) void pool_kernel(const float* __restrict__ H,
                                                   const int* __restrict__ batch,
                                                   float* __restrict__ gsum, int n) {
    const int c = threadIdx.x;            // 0..127
    const int n0 = blockIdx.x * 128;
    if (n0 >= n) return;
    const int n1 = min(n0 + 128, n);
    float acc = 0.f;
    int cg = batch[n0];
    for (int i = n0; i < n1; ++i) {
        int g = batch[i];
        if (g != cg) {
            atomicAdd(&gsum[cg * HCDIM + c], acc);
            acc = 0.f;
            cg = g;
        }
        acc += H[(long)i * HCDIM + c];
    }
    atomicAdd(&gsum[cg * HCDIM + c], acc);
}

__global__ __launch_bounds__(64) void mlp_kernel(const float* __restrict__ gsum,
                                                 const int* __restrict__ gstart,
                                                 const float* __restrict__ fw1,
                                                 const float* __restrict__ fb1,
                                                 const float* __restrict__ fw2,
                                                 const float* __restrict__ fb2,
                                                 float* __restrict__ out) {
    const int g = blockIdx.x;
    const int j = threadIdx.x;            // 0..63
    __shared__ float emb[HCDIM];
    __shared__ float gh[64];
    int cnt = gstart[g + 1] - gstart[g];
    float invc = 1.f / fmaxf((float)cnt, 1.f);
    emb[j] = gsum[g * HCDIM + j] * invc;
    emb[j + 64] = gsum[g * HCDIM + 64 + j] * invc;
    __syncthreads();
    float a = fb1[j];
    for (int k = 0; k < HCDIM; ++k) a += emb[k] * fw1[k * 64 + j];
    gh[j] = fmaxf(a, 0.f);
    __syncthreads();
    if (j < 2) {
        float o = fb2[j];
        for (int k = 0; k < 64; ++k) o += gh[k] * fw2[k * 2 + j];
        out[g * 2 + j] = o;
    }
}

// ---------------------------------------------------------------- launcher

extern "C" void kernel_launch(void* const* d_in, const int* in_sizes, int n_in,
                              void* d_out, int out_size, void* d_ws, size_t ws_size,
                              hipStream_t stream) {
    const float* x     = (const float*)d_in[0];
    const int*   eidx  = (const int*)d_in[1];
    const float* eattr = (const float*)d_in[2];
    const int*   batch = (const int*)d_in[3];
    const float* w1  = (const float*)d_in[4];
    const float* as1 = (const float*)d_in[5];
    const float* ad1 = (const float*)d_in[6];
    const float* we1 = (const float*)d_in[7];
    const float* ae1 = (const float*)d_in[8];
    const float* b1  = (const float*)d_in[9];
    const float* w2  = (const float*)d_in[10];
    const float* as2 = (const float*)d_in[11];
    const float* ad2 = (const float*)d_in[12];
    const float* we2 = (const float*)d_in[13];
    const float* ae2 = (const float*)d_in[14];
    const float* b2  = (const float*)d_in[15];
    const float* w3  = (const float*)d_in[16];
    const float* as3 = (const float*)d_in[17];
    const float* ad3 = (const float*)d_in[18];
    const float* we3 = (const float*)d_in[19];
    const float* ae3 = (const float*)d_in[20];
    const float* b3  = (const float*)d_in[21];
    const float* fw1 = (const float*)d_in[22];
    const float* fb1 = (const float*)d_in[23];
    const float* fw2 = (const float*)d_in[24];
    const float* fb2 = (const float*)d_in[25];

    const int N = in_sizes[3];
    const int E = in_sizes[2];
    const int* src = eidx;
    const int* dst = eidx + E;

    // workspace carve
    char* p = (char*)d_ws;
    auto alloc = [&](size_t bytes) {
        void* r = (void*)p;
        p += (bytes + 255) & ~(size_t)255;
        return r;
    };
    float* A      = (float*)alloc((size_t)N * HCDIM * 4);
    // B region: bf16 hi/lo pair (layers 1-2) ALIASED with fp32 (layer 3 -> pool).
    char*  Bbuf   = (char*)alloc((size_t)N * HCDIM * 4);
    unsigned short* Bhi = (unsigned short*)Bbuf;
    unsigned short* Blo = Bhi + (size_t)N * HCDIM;
    float* Bf32   = (float*)Bbuf;
    float* asrc   = (float*)alloc((size_t)N * NHEAD * 4);
    float* adst   = (float*)alloc((size_t)N * NHEAD * 4);
    int*   deg    = (int*)alloc((size_t)N * 4);
    int*   eoff   = (int*)alloc((size_t)(N + 1) * 4);
    int*   cursor = (int*)alloc((size_t)N * 4);
    int2*  epack  = (int2*)alloc((size_t)E * 8);
    float* sume   = (float*)alloc((size_t)N * 4);
    float* floop  = (float*)alloc((size_t)N * 4);
    int*   bsum   = (int*)alloc(((size_t)(N + 255) / 256) * 4);
    float* kc     = (float*)alloc(24 * 4);
    int*   gstart = (int*)alloc((NGRAPH + 1) * 4);
    float* gsum   = (float*)alloc(NGRAPH * HCDIM * 4);
    unsigned short* wt2h = (unsigned short*)alloc(HCDIM * HCDIM * 2);
    unsigned short* wt2l = (unsigned short*)alloc(HCDIM * HCDIM * 2);
    unsigned short* wt3h = (unsigned short*)alloc(HCDIM * HCDIM * 2);
    unsigned short* wt3l = (unsigned short*)alloc(HCDIM * HCDIM * 2);

    const int NB = (N + 255) / 256;
    const int EB = (E + 255) / 256;
    const int AGG_BLOCKS = (((N + 1) / 2) * 64 + 255) / 256;   // 2 nodes/wave
    const int GEMM_BLOCKS = (N + 127) / 128;                   // 128 rows per block

    setup0<<<NB, 256, 0, stream>>>(deg, sume, cursor, gsum,
                                   w2, w3, wt2h, wt2l, wt3h, wt3l,
                                   we1, ae1, we2, ae2, we3, ae3, kc,
                                   batch, gstart, N);
    count_deg<<<EB, 256, 0, stream>>>(dst, eattr, deg, sume, E);
    block_sum<<<NB, 256, 0, stream>>>(deg, bsum, N);
    scan_bsums<<<1, 512, 0, stream>>>(bsum, NB);
    scan_final<<<NB, 256, 0, stream>>>(deg, bsum, sume, eoff, floop, N);
    scatter_edges<<<EB, 256, 0, stream>>>(src, dst, eattr, eoff, cursor, epack, E);

    // layer 1 (no self loops): lin + attn fused; out -> bf16 hi/lo
    lin4_attn<<<(N * 64 + 255) / 256, 256, 0, stream>>>(x, w1, as1, ad1, A, asrc, adst, N);
    gat_aggregate<<<AGG_BLOCKS, 256, 0, stream>>>(A, asrc, adst, epack, eoff,
                                                  kc + 0, b1, floop, Bf32, Bhi, Blo, N, 0, 1);
    // layer 2 (self loops, fill=mean): out -> bf16 hi/lo
    gemm_mfma<<<GEMM_BLOCKS, 256, 0, stream>>>(Bhi, Blo, wt2h, wt2l, A, N);
    attn_coeff<<<(N * 8 + 255) / 256, 256, 0, stream>>>(A, as2, ad2, asrc, adst, N);
    gat_aggregate<<<AGG_BLOCKS, 256, 0, stream>>>(A, asrc, adst, epack, eoff,
                                                  kc + 8, b2, floop, Bf32, Bhi, Blo, N, 1, 1);
    // layer 3: out -> fp32 (pool consumes)
    gemm_mfma<<<GEMM_BLOCKS, 256, 0, stream>>>(Bhi, Blo, wt3h, wt3l, A, N);
    attn_coeff<<<(N * 8 + 255) / 256, 256, 0, stream>>>(A, as3, ad3, asrc, adst, N);
    gat_aggregate<<<AGG_BLOCKS, 256, 0, stream>>>(A, asrc, adst, epack, eoff,
                                                  kc + 16, b3, floop, Bf32, Bhi, Blo, N, 1, 0);

    // mean-pool + MLP head
    pool_kernel<<<(N + 127) / 128, 128, 0, stream>>>(Bf32, batch, gsum, N);
    mlp_kernel<<<NGRAPH, 64, 0, stream>>>(gsum, gstart, fw1, fb1, fw2, fb2, (float*)d_out);
}

// Round 5
// 560.655 us; speedup vs baseline: 1.7591x; 1.0502x over previous
//
#include <hip/hip_runtime.h>
#include <hip/hip_bf16.h>
#include <math.h>

#define NHEAD 8
#define CDIM 16
#define HCDIM 128
#define NGRAPH 64

typedef __attribute__((ext_vector_type(8))) short short8;
typedef __attribute__((ext_vector_type(4))) float f32x4;

static __device__ __forceinline__ unsigned short f2bf(float f) {
    unsigned u = __float_as_uint(f);
    unsigned r = (u + 0x7FFF + ((u >> 16) & 1)) >> 16;   // rne
    return (unsigned short)r;
}
static __device__ __forceinline__ float bf2f(unsigned short s) {
    return __uint_as_float(((unsigned)s) << 16);
}

// ---------------------------------------------------------------- setup

// merged: zero deg/cursor/gsum + split w2/w3 + kcoef + graph_bounds
// + attw[l][t][h][k] = sum_c W_l[k][h*16+c] * a_{s/d}_l[h][c]   (4096 floats)
__global__ void setup0(int* __restrict__ deg, int* __restrict__ cursor,
                       float* __restrict__ gsum,
                       const float* __restrict__ w2, const float* __restrict__ w3,
                       unsigned short* __restrict__ wt2h, unsigned short* __restrict__ wt2l,
                       unsigned short* __restrict__ wt3h, unsigned short* __restrict__ wt3l,
                       const float* __restrict__ we1, const float* __restrict__ ae1,
                       const float* __restrict__ we2, const float* __restrict__ ae2,
                       const float* __restrict__ we3, const float* __restrict__ ae3,
                       float* __restrict__ kc,
                       const float* __restrict__ as2, const float* __restrict__ ad2,
                       const float* __restrict__ as3, const float* __restrict__ ad3,
                       float* __restrict__ attw,
                       const int* __restrict__ batch, int* __restrict__ gstart, int n) {
    int i = blockIdx.x * 256 + threadIdx.x;
    if (i < n) { deg[i] = 0; cursor[i] = 0; }
    if (i < NGRAPH * HCDIM) gsum[i] = 0.f;
    if (i < HCDIM * HCDIM) {
        int k = i >> 7, nn = i & 127;
        float v = w2[i];
        unsigned short h = f2bf(v);
        wt2h[nn * HCDIM + k] = h;
        wt2l[nn * HCDIM + k] = f2bf(v - bf2f(h));
        v = w3[i];
        h = f2bf(v);
        wt3h[nn * HCDIM + k] = h;
        wt3l[nn * HCDIM + k] = f2bf(v - bf2f(h));
    }
    if (i < 4096) {   // attw: l=(i>>11)&1 (0->layer2,1->layer3), t=(i>>10)&1 (0=src,1=dst)
        int l = (i >> 11) & 1, t = (i >> 10) & 1, h = (i >> 7) & 7, k = i & 127;
        const float* w = l ? w3 : w2;
        const float* a = l ? (t ? ad3 : as3) : (t ? ad2 : as2);
        float s = 0.f;
#pragma unroll
        for (int c = 0; c < CDIM; ++c) s += w[k * HCDIM + h * CDIM + c] * a[h * CDIM + c];
        attw[i] = s;
    }
    if (i < 24) {
        int l = i >> 3, h = i & 7;
        const float* we = (l == 0) ? we1 : ((l == 1) ? we2 : we3);
        const float* ae = (l == 0) ? ae1 : ((l == 1) ? ae2 : ae3);
        float s = 0.f;
        for (int c = 0; c < CDIM; ++c) s += we[h * CDIM + c] * ae[h * CDIM + c];
        kc[i] = s;
    }
    if (i >= 4352 && i <= 4352 + NGRAPH) {   // graph bounds, disjoint thread range
        int g = i - 4352;
        int lo = 0, hi = n;
        while (lo < hi) {
            int mid = (lo + hi) >> 1;
            if (batch[mid] < g) lo = mid + 1; else hi = mid;
        }
        gstart[g] = lo;
    }
}

__global__ void count_deg(const int* __restrict__ dst, int* __restrict__ deg, int E) {
    int e = blockIdx.x * 256 + threadIdx.x;
    if (e >= E) return;
    atomicAdd(&deg[dst[e]], 1);
}

__global__ void block_sum(const int* __restrict__ deg, int* __restrict__ bsum, int n) {
    __shared__ int s[256];
    int i = blockIdx.x * 256 + threadIdx.x;
    s[threadIdx.x] = (i < n) ? deg[i] : 0;
    __syncthreads();
    for (int off = 128; off > 0; off >>= 1) {
        if (threadIdx.x < off) s[threadIdx.x] += s[threadIdx.x + off];
        __syncthreads();
    }
    if (threadIdx.x == 0) bsum[blockIdx.x] = s[0];
}

__global__ void scan_bsums(int* __restrict__ bsum, int nb) {
    __shared__ int s[512];
    int t = threadIdx.x;
    int v = (t < nb) ? bsum[t] : 0;
    s[t] = v;
    __syncthreads();
    for (int off = 1; off < 512; off <<= 1) {
        int add = (t >= off) ? s[t - off] : 0;
        __syncthreads();
        s[t] += add;
        __syncthreads();
    }
    if (t < nb) bsum[t] = s[t] - v;   // exclusive base per block
}

__global__ void scan_final(const int* __restrict__ deg, const int* __restrict__ bbase,
                           int* __restrict__ eoff, int n) {
    __shared__ int s[256];
    int i = blockIdx.x * 256 + threadIdx.x;
    int v = (i < n) ? deg[i] : 0;
    s[threadIdx.x] = v;
    __syncthreads();
    for (int off = 1; off < 256; off <<= 1) {
        int add = (threadIdx.x >= off) ? s[threadIdx.x - off] : 0;
        __syncthreads();
        s[threadIdx.x] += add;
        __syncthreads();
    }
    if (i < n) eoff[i + 1] = bbase[blockIdx.x] + s[threadIdx.x];
    if (i == 0) eoff[0] = 0;
}

// writes dst-sorted packed edges: epack[p] = {src, bits(eattr)}
__global__ void scatter_edges(const int* __restrict__ src, const int* __restrict__ dst,
                              const float* __restrict__ eattr,
                              const int* __restrict__ eoff,
                              int* __restrict__ cursor, int2* __restrict__ epack, int E) {
    int e = blockIdx.x * 256 + threadIdx.x;
    if (e >= E) return;
    int d = dst[e];
    int p = eoff[d] + atomicAdd(&cursor[d], 1);
    epack[p] = make_int2(src[e], __float_as_int(eattr[e]));
}

// ---------------------------------------------------------------- dense lins

// layer 1: [n,4] @ [4,128], fused with attn-coeff (8-lane shuffle reduction)
__global__ __launch_bounds__(256) void lin4_attn(const float* __restrict__ X,
                                                 const float* __restrict__ W,
                                                 const float* __restrict__ as_,
                                                 const float* __restrict__ ad_,
                                                 float* __restrict__ Y,
                                                 float* __restrict__ asrc,
                                                 float* __restrict__ adst, int n) {
    int gid = blockIdx.x * 256 + threadIdx.x;
    int node = gid >> 6;
    if (node >= n) return;
    int lane = threadIdx.x & 63;
    int c0 = lane * 2;
    float4 xv = *(const float4*)(X + (long)node * 4);
    float a0 = xv.x * W[c0]       + xv.y * W[128 + c0]     + xv.z * W[256 + c0]     + xv.w * W[384 + c0];
    float a1 = xv.x * W[c0 + 1]   + xv.y * W[128 + c0 + 1] + xv.z * W[256 + c0 + 1] + xv.w * W[384 + c0 + 1];
    *(float2*)(Y + (long)node * HCDIM + c0) = make_float2(a0, a1);

    int h = lane >> 3;
    int cc = c0 & 15;
    float ps = a0 * as_[h * CDIM + cc] + a1 * as_[h * CDIM + cc + 1];
    float pd = a0 * ad_[h * CDIM + cc] + a1 * ad_[h * CDIM + cc + 1];
    ps += __shfl_xor(ps, 1); ps += __shfl_xor(ps, 2); ps += __shfl_xor(ps, 4);
    pd += __shfl_xor(pd, 1); pd += __shfl_xor(pd, 2); pd += __shfl_xor(pd, 4);
    if ((lane & 7) == 0) {
        asrc[node * NHEAD + h] = ps;
        adst[node * NHEAD + h] = pd;
    }
}

// layers 2/3: [n,128] @ [128,128] via split-bf16 MFMA.
__global__ __launch_bounds__(256) void gemm_mfma(const unsigned short* __restrict__ Ahi,
                                                 const unsigned short* __restrict__ Alo,
                                                 const unsigned short* __restrict__ Wth,
                                                 const unsigned short* __restrict__ Wtl,
                                                 float* __restrict__ Y, int n) {
    const int wave = threadIdx.x >> 6;
    const int lane = threadIdx.x & 63;
    const int quad = lane >> 4;
    const int l16  = lane & 15;
    const int rowbase = (blockIdx.x * 8 + wave * 2) * 16;

    f32x4 acc[2][8];
#pragma unroll
    for (int r = 0; r < 2; ++r)
#pragma unroll
        for (int t = 0; t < 8; ++t) acc[r][t] = (f32x4){0.f, 0.f, 0.f, 0.f};

#pragma unroll
    for (int kb = 0; kb < HCDIM; kb += 32) {
        short8 ah[2], al[2];
#pragma unroll
        for (int r = 0; r < 2; ++r) {
            int row = rowbase + r * 16 + l16;
            row = (row < n) ? row : (n - 1);
            const long off = (long)row * HCDIM + kb + quad * 8;
            ah[r] = *(const short8*)(Ahi + off);
            al[r] = *(const short8*)(Alo + off);
        }
#pragma unroll
        for (int nt = 0; nt < 8; ++nt) {
            const long woff = (long)(nt * 16 + l16) * HCDIM + kb + quad * 8;
            short8 bh = *(const short8*)(Wth + woff);
            short8 bl = *(const short8*)(Wtl + woff);
#pragma unroll
            for (int r = 0; r < 2; ++r) {
                acc[r][nt] = __builtin_amdgcn_mfma_f32_16x16x32_bf16(ah[r], bh, acc[r][nt], 0, 0, 0);
                acc[r][nt] = __builtin_amdgcn_mfma_f32_16x16x32_bf16(al[r], bh, acc[r][nt], 0, 0, 0);
                acc[r][nt] = __builtin_amdgcn_mfma_f32_16x16x32_bf16(ah[r], bl, acc[r][nt], 0, 0, 0);
            }
        }
    }

    // C/D layout: col = l16, row_local = quad*4 + reg
#pragma unroll
    for (int r = 0; r < 2; ++r) {
#pragma unroll
        for (int reg = 0; reg < 4; ++reg) {
            int row = rowbase + r * 16 + quad * 4 + reg;
            if (row < n) {
                float* yp = Y + (long)row * HCDIM + l16;
#pragma unroll
                for (int nt = 0; nt < 8; ++nt) yp[nt * 16] = acc[r][nt][reg];
            }
        }
    }
}

// ---------------------------------------------------------------- aggregate

// TWO nodes per wave (32 lanes x float4 channels each); single pass,
// no max-subtraction (alpha is O(1): exp(a)/sum exp(a) identical).
// epack double-buffered (prefetch next 4 while gathering current 4).
// floop (self-loop attr = mean eattr) computed in-wave from the edges.
// compute_next: fused next-layer attn coeffs via asrc' = B @ (W'·a') using
// precomputed wasn/wadn [8][128]; 32-lane shfl reduction.
__global__ __launch_bounds__(256) void gat_aggregate(
    const float* __restrict__ hlin,     // [n,128]
    const float* __restrict__ asrc,     // [n,8]
    const float* __restrict__ adst,     // [n,8]
    const int2*  __restrict__ epack,    // [E] dst-sorted {src, bits(eattr)}
    const int*   __restrict__ eoff,     // [n+1]
    const float* __restrict__ kc,       // [8] this layer
    const float* __restrict__ bias,     // [128]
    const float* __restrict__ wasn,     // [8][128] next-layer src table
    const float* __restrict__ wadn,     // [8][128] next-layer dst table
    float* __restrict__ asrcn,          // [n,8] next-layer coeffs out
    float* __restrict__ adstn,
    float* __restrict__ outf,           // [n,128] (split_out=0)
    unsigned short* __restrict__ outhi, // [n,128] (split_out=1)
    unsigned short* __restrict__ outlo,
    int n, int use_loop, int split_out, int compute_next) {
    const int lane = threadIdx.x & 63;
    const int hl = lane & 31;
    int nid = ((blockIdx.x * 256 + threadIdx.x) >> 6) * 2 + (lane >> 5);
    if (nid >= n) return;
    const int h = hl >> 2;            // 4 lanes per head
    const int c0 = hl * 4;            // 4 contiguous channels per lane

    const float adst_h = adst[nid * NHEAD + h];
    const float k_h = kc[h];
    const int e0 = eoff[nid], e1 = eoff[nid + 1];

    float den = 0.f, sume = 0.f;
    float ax = 0.f, ay = 0.f, az = 0.f, aw = 0.f;

    if (e0 < e1) {
        int2 ep[4];
#pragma unroll
        for (int j = 0; j < 4; ++j) {
            int idx = e0 + j; idx = (idx < e1) ? idx : (e1 - 1);
            ep[j] = epack[idx];
        }
        for (int base = e0; base < e1; base += 4) {
            int2 epn[4];
#pragma unroll
            for (int j = 0; j < 4; ++j) {           // prefetch next batch
                int idx = base + 4 + j; idx = (idx < e1) ? idx : (e1 - 1);
                epn[j] = epack[idx];
            }
            float av[4]; float4 hv[4];
#pragma unroll
            for (int j = 0; j < 4; ++j) {
                av[j] = asrc[ep[j].x * NHEAD + h];
                hv[j] = *(const float4*)(hlin + (long)ep[j].x * HCDIM + c0);
            }
#pragma unroll
            for (int j = 0; j < 4; ++j) {
                bool valid = (base + j < e1);
                float ea = __int_as_float(ep[j].y);
                float a = av[j] + adst_h + ea * k_h;
                a = (a > 0.f) ? a : 0.2f * a;
                float w = valid ? __expf(a) : 0.f;
                sume += valid ? ea : 0.f;
                den += w;
                ax += hv[j].x * w; ay += hv[j].y * w; az += hv[j].z * w; aw += hv[j].w * w;
            }
#pragma unroll
            for (int j = 0; j < 4; ++j) ep[j] = epn[j];
        }
    }

    if (use_loop) {   // self-loop processed last; attr = mean of incoming eattr
        float fl = sume / fmaxf((float)(e1 - e0), 1.f);
        float a = asrc[nid * NHEAD + h] + adst_h + fl * k_h;
        a = (a > 0.f) ? a : 0.2f * a;
        float w = __expf(a);
        float4 hv = *(const float4*)(hlin + (long)nid * HCDIM + c0);
        den += w; ax += hv.x * w; ay += hv.y * w; az += hv.z * w; aw += hv.w * w;
    }

    float inv = 1.f / (den + 1e-16f);
    float4 bv = *(const float4*)(bias + c0);
    float o0 = fmaxf(ax * inv + bv.x, 0.f);
    float o1 = fmaxf(ay * inv + bv.y, 0.f);
    float o2 = fmaxf(az * inv + bv.z, 0.f);
    float o3 = fmaxf(aw * inv + bv.w, 0.f);
    if (split_out) {
        unsigned short h0 = f2bf(o0), h1 = f2bf(o1), h2 = f2bf(o2), h3 = f2bf(o3);
        ushort4 hi = make_ushort4(h0, h1, h2, h3);
        ushort4 lo = make_ushort4(f2bf(o0 - bf2f(h0)), f2bf(o1 - bf2f(h1)),
                                  f2bf(o2 - bf2f(h2)), f2bf(o3 - bf2f(h3)));
        *(ushort4*)(outhi + (long)nid * HCDIM + c0) = hi;
        *(ushort4*)(outlo + (long)nid * HCDIM + c0) = lo;
    } else {
        *(float4*)(outf + (long)nid * HCDIM + c0) = make_float4(o0, o1, o2, o3);
    }

    if (compute_next) {   // asrc'[nid][h2] = sum_k B[nid][k]*wasn[h2][k]
        float ps[8], pd[8];
#pragma unroll
        for (int h2 = 0; h2 < 8; ++h2) {
            const float* wsp = wasn + h2 * HCDIM + c0;
            const float* wdp = wadn + h2 * HCDIM + c0;
            ps[h2] = o0 * wsp[0] + o1 * wsp[1] + o2 * wsp[2] + o3 * wsp[3];
            pd[h2] = o0 * wdp[0] + o1 * wdp[1] + o2 * wdp[2] + o3 * wdp[3];
        }
#pragma unroll
        for (int h2 = 0; h2 < 8; ++h2) {
#pragma unroll
            for (int m = 1; m < 32; m <<= 1) {
                ps[h2] += __shfl_xor(ps[h2], m);
                pd[h2] += __shfl_xor(pd[h2], m);
            }
        }
        if (hl == 0) {
            *(float4*)(asrcn + nid * NHEAD)     = make_float4(ps[0], ps[1], ps[2], ps[3]);
            *(float4*)(asrcn + nid * NHEAD + 4) = make_float4(ps[4], ps[5], ps[6], ps[7]);
            *(float4*)(adstn + nid * NHEAD)     = make_float4(pd[0], pd[1], pd[2], pd[3]);
            *(float4*)(adstn + nid * NHEAD + 4) = make_float4(pd[4], pd[5], pd[6], pd[7]);
        }
    }
}

// ---------------------------------------------------------------- pool + MLP

__global__ __launch_bounds__(128) void pool_kernel(const float* __restrict__ H,
                                                   const int* __restrict__ batch,
                                                   float* __restrict__ gsum, int n) {
    const int c = threadIdx.x;            // 0..127
    const int n0 = blockIdx.x * 128;
    if (n0 >= n) return;
    const int n1 = min(n0 + 128, n);
    float acc = 0.f;
    int cg = batch[n0];
    for (int i = n0; i < n1; ++i) {
        int g = batch[i];
        if (g != cg) {
            atomicAdd(&gsum[cg * HCDIM + c], acc);
            acc = 0.f;
            cg = g;
        }
        acc += H[(long)i * HCDIM + c];
    }
    atomicAdd(&gsum[cg * HCDIM + c], acc);
}

__global__ __launch_bounds__(64) void mlp_kernel(const float* __restrict__ gsum,
                                                 const int* __restrict__ gstart,
                                                 const float* __restrict__ fw1,
                                                 const float* __restrict__ fb1,
                                                 const float* __restrict__ fw2,
                                                 const float* __restrict__ fb2,
                                                 float* __restrict__ out) {
    const int g = blockIdx.x;
    const int j = threadIdx.x;            // 0..63
    __shared__ float emb[HCDIM];
    __shared__ float gh[64];
    int cnt = gstart[g + 1] - gstart[g];
    float invc = 1.f / fmaxf((float)cnt, 1.f);
    emb[j] = gsum[g * HCDIM + j] * invc;
    emb[j + 64] = gsum[g * HCDIM + 64 + j] * invc;
    __syncthreads();
    float a = fb1[j];
    for (int k = 0; k < HCDIM; ++k) a += emb[k] * fw1[k * 64 + j];
    gh[j] = fmaxf(a, 0.f);
    __syncthreads();
    if (j < 2) {
        float o = fb2[j];
        for (int k = 0; k < 64; ++k) o += gh[k] * fw2[k * 2 + j];
        out[g * 2 + j] = o;
    }
}

// ---------------------------------------------------------------- launcher

extern "C" void kernel_launch(void* const* d_in, const int* in_sizes, int n_in,
                              void* d_out, int out_size, void* d_ws, size_t ws_size,
                              hipStream_t stream) {
    const float* x     = (const float*)d_in[0];
    const int*   eidx  = (const int*)d_in[1];
    const float* eattr = (const float*)d_in[2];
    const int*   batch = (const int*)d_in[3];
    const float* w1  = (const float*)d_in[4];
    const float* as1 = (const float*)d_in[5];
    const float* ad1 = (const float*)d_in[6];
    const float* we1 = (const float*)d_in[7];
    const float* ae1 = (const float*)d_in[8];
    const float* b1  = (const float*)d_in[9];
    const float* w2  = (const float*)d_in[10];
    const float* as2 = (const float*)d_in[11];
    const float* ad2 = (const float*)d_in[12];
    const float* we2 = (const float*)d_in[13];
    const float* ae2 = (const float*)d_in[14];
    const float* b2  = (const float*)d_in[15];
    const float* w3  = (const float*)d_in[16];
    const float* as3 = (const float*)d_in[17];
    const float* ad3 = (const float*)d_in[18];
    const float* we3 = (const float*)d_in[19];
    const float* ae3 = (const float*)d_in[20];
    const float* b3  = (const float*)d_in[21];
    const float* fw1 = (const float*)d_in[22];
    const float* fb1 = (const float*)d_in[23];
    const float* fw2 = (const float*)d_in[24];
    const float* fb2 = (const float*)d_in[25];

    const int N = in_sizes[3];
    const int E = in_sizes[2];
    const int* src = eidx;
    const int* dst = eidx + E;

    // workspace carve
    char* p = (char*)d_ws;
    auto alloc = [&](size_t bytes) {
        void* r = (void*)p;
        p += (bytes + 255) & ~(size_t)255;
        return r;
    };
    float* A      = (float*)alloc((size_t)N * HCDIM * 4);
    // B region: bf16 hi/lo pair (layers 1-2) ALIASED with fp32 (layer 3 -> pool).
    char*  Bbuf   = (char*)alloc((size_t)N * HCDIM * 4);
    unsigned short* Bhi = (unsigned short*)Bbuf;
    unsigned short* Blo = Bhi + (size_t)N * HCDIM;
    float* Bf32   = (float*)Bbuf;
    float* asrcA  = (float*)alloc((size_t)N * NHEAD * 4);
    float* adstA  = (float*)alloc((size_t)N * NHEAD * 4);
    float* asrcB  = (float*)alloc((size_t)N * NHEAD * 4);
    float* adstB  = (float*)alloc((size_t)N * NHEAD * 4);
    int*   deg    = (int*)alloc((size_t)N * 4);
    int*   eoff   = (int*)alloc((size_t)(N + 1) * 4);
    int*   cursor = (int*)alloc((size_t)N * 4);
    int2*  epack  = (int2*)alloc((size_t)E * 8);
    int*   bsum   = (int*)alloc(((size_t)(N + 255) / 256) * 4);
    float* kc     = (float*)alloc(24 * 4);
    float* attw   = (float*)alloc(4096 * 4);   // [l][t][h][k]
    int*   gstart = (int*)alloc((NGRAPH + 1) * 4);
    float* gsum   = (float*)alloc(NGRAPH * HCDIM * 4);
    unsigned short* wt2h = (unsigned short*)alloc(HCDIM * HCDIM * 2);
    unsigned short* wt2l = (unsigned short*)alloc(HCDIM * HCDIM * 2);
    unsigned short* wt3h = (unsigned short*)alloc(HCDIM * HCDIM * 2);
    unsigned short* wt3l = (unsigned short*)alloc(HCDIM * HCDIM * 2);

    const int NB = (N + 255) / 256;
    const int EB = (E + 255) / 256;
    const int AGG_BLOCKS = (((N + 1) / 2) * 64 + 255) / 256;   // 2 nodes/wave
    const int GEMM_BLOCKS = (N + 127) / 128;                   // 128 rows per block

    setup0<<<NB, 256, 0, stream>>>(deg, cursor, gsum,
                                   w2, w3, wt2h, wt2l, wt3h, wt3l,
                                   we1, ae1, we2, ae2, we3, ae3, kc,
                                   as2, ad2, as3, ad3, attw,
                                   batch, gstart, N);
    count_deg<<<EB, 256, 0, stream>>>(dst, deg, E);
    block_sum<<<NB, 256, 0, stream>>>(deg, bsum, N);
    scan_bsums<<<1, 512, 0, stream>>>(bsum, NB);
    scan_final<<<NB, 256, 0, stream>>>(deg, bsum, eoff, N);
    scatter_edges<<<EB, 256, 0, stream>>>(src, dst, eattr, eoff, cursor, epack, E);

    // layer 1 (no self loops): lin + attn fused; agg emits bf16 hi/lo + layer2 coeffs
    lin4_attn<<<(N * 64 + 255) / 256, 256, 0, stream>>>(x, w1, as1, ad1, A, asrcA, adstA, N);
    gat_aggregate<<<AGG_BLOCKS, 256, 0, stream>>>(A, asrcA, adstA, epack, eoff,
                                                  kc + 0, b1, attw + 0, attw + 1024,
                                                  asrcB, adstB,
                                                  Bf32, Bhi, Blo, N, 0, 1, 1);
    // layer 2 (self loops, fill=mean): agg emits bf16 hi/lo + layer3 coeffs
    gemm_mfma<<<GEMM_BLOCKS, 256, 0, stream>>>(Bhi, Blo, wt2h, wt2l, A, N);
    gat_aggregate<<<AGG_BLOCKS, 256, 0, stream>>>(A, asrcB, adstB, epack, eoff,
                                                  kc + 8, b2, attw + 2048, attw + 3072,
                                                  asrcA, adstA,
                                                  Bf32, Bhi, Blo, N, 1, 1, 1);
    // layer 3: out -> fp32 (pool consumes)
    gemm_mfma<<<GEMM_BLOCKS, 256, 0, stream>>>(Bhi, Blo, wt3h, wt3l, A, N);
    gat_aggregate<<<AGG_BLOCKS, 256, 0, stream>>>(A, asrcA, adstA, epack, eoff,
                                                  kc + 16, b3, attw, attw,
                                                  asrcB, adstB,
                                                  Bf32, Bhi, Blo, N, 1, 0, 0);

    // mean-pool + MLP head
    pool_kernel<<<(N + 127) / 128, 128, 0, stream>>>(Bf32, batch, gsum, N);
    mlp_kernel<<<NGRAPH, 64, 0, stream>>>(gsum, gstart, fw1, fb1, fw2, fb2, (float*)d_out);
}

// Round 6
// 535.912 us; speedup vs baseline: 1.8404x; 1.0462x over previous
//
#include <hip/hip_runtime.h>
#include <hip/hip_bf16.h>
#include <math.h>

#define NHEAD 8
#define CDIM 16
#define HCDIM 128
#define NGRAPH 64
#define WEXT 144   // 128 gemm cols + 8 src-coeff cols + 8 dst-coeff cols

typedef __attribute__((ext_vector_type(8))) short short8;
typedef __attribute__((ext_vector_type(4))) float f32x4;

static __device__ __forceinline__ unsigned short f2bf(float f) {
    unsigned u = __float_as_uint(f);
    unsigned r = (u + 0x7FFF + ((u >> 16) & 1)) >> 16;   // rne
    return (unsigned short)r;
}
static __device__ __forceinline__ float bf2f(unsigned short s) {
    return __uint_as_float(((unsigned)s) << 16);
}

// ---------------------------------------------------------------- setup

// merged: zero deg/cursor/gsum + kcoef + graph_bounds + extended weight build:
// wt[l][nn][k] (nn<128: W_l[k][nn]; nn in 128..135: (W_l·as_l)[k] for head nn-128;
//               nn in 136..143: (W_l·ad_l)[k]), split into bf16 hi/lo, transposed.
__global__ void setup0(int* __restrict__ deg, int* __restrict__ cursor,
                       float* __restrict__ gsum,
                       const float* __restrict__ w2, const float* __restrict__ w3,
                       unsigned short* __restrict__ wt2h, unsigned short* __restrict__ wt2l,
                       unsigned short* __restrict__ wt3h, unsigned short* __restrict__ wt3l,
                       const float* __restrict__ we1, const float* __restrict__ ae1,
                       const float* __restrict__ we2, const float* __restrict__ ae2,
                       const float* __restrict__ we3, const float* __restrict__ ae3,
                       float* __restrict__ kc,
                       const float* __restrict__ as2, const float* __restrict__ ad2,
                       const float* __restrict__ as3, const float* __restrict__ ad3,
                       const int* __restrict__ batch, int* __restrict__ gstart, int n) {
    int i = blockIdx.x * 256 + threadIdx.x;
    if (i < n) { deg[i] = 0; cursor[i] = 0; }
    if (i < NGRAPH * HCDIM) gsum[i] = 0.f;
    if (i < WEXT * HCDIM) {
        int nn = i >> 7, k = i & 127;
        float v2, v3;
        if (nn < HCDIM) {
            v2 = w2[k * HCDIM + nn];
            v3 = w3[k * HCDIM + nn];
        } else if (nn < HCDIM + NHEAD) {
            int h = nn - HCDIM;
            float s2 = 0.f, s3 = 0.f;
#pragma unroll
            for (int c = 0; c < CDIM; ++c) {
                s2 += w2[k * HCDIM + h * CDIM + c] * as2[h * CDIM + c];
                s3 += w3[k * HCDIM + h * CDIM + c] * as3[h * CDIM + c];
            }
            v2 = s2; v3 = s3;
        } else {
            int h = nn - HCDIM - NHEAD;
            float s2 = 0.f, s3 = 0.f;
#pragma unroll
            for (int c = 0; c < CDIM; ++c) {
                s2 += w2[k * HCDIM + h * CDIM + c] * ad2[h * CDIM + c];
                s3 += w3[k * HCDIM + h * CDIM + c] * ad3[h * CDIM + c];
            }
            v2 = s2; v3 = s3;
        }
        unsigned short h2 = f2bf(v2);
        wt2h[nn * HCDIM + k] = h2;
        wt2l[nn * HCDIM + k] = f2bf(v2 - bf2f(h2));
        unsigned short h3 = f2bf(v3);
        wt3h[nn * HCDIM + k] = h3;
        wt3l[nn * HCDIM + k] = f2bf(v3 - bf2f(h3));
    }
    if (i < 24) {
        int l = i >> 3, h = i & 7;
        const float* we = (l == 0) ? we1 : ((l == 1) ? we2 : we3);
        const float* ae = (l == 0) ? ae1 : ((l == 1) ? ae2 : ae3);
        float s = 0.f;
        for (int c = 0; c < CDIM; ++c) s += we[h * CDIM + c] * ae[h * CDIM + c];
        kc[i] = s;
    }
    if (i >= 18560 && i <= 18560 + NGRAPH) {   // graph bounds, disjoint range
        int g = i - 18560;
        int lo = 0, hi = n;
        while (lo < hi) {
            int mid = (lo + hi) >> 1;
            if (batch[mid] < g) lo = mid + 1; else hi = mid;
        }
        gstart[g] = lo;
    }
}

__global__ void count_deg(const int* __restrict__ dst, int* __restrict__ deg, int E) {
    int e = blockIdx.x * 256 + threadIdx.x;
    if (e >= E) return;
    atomicAdd(&deg[dst[e]], 1);
}

__global__ void block_sum(const int* __restrict__ deg, int* __restrict__ bsum, int n) {
    __shared__ int s[256];
    int i = blockIdx.x * 256 + threadIdx.x;
    s[threadIdx.x] = (i < n) ? deg[i] : 0;
    __syncthreads();
    for (int off = 128; off > 0; off >>= 1) {
        if (threadIdx.x < off) s[threadIdx.x] += s[threadIdx.x + off];
        __syncthreads();
    }
    if (threadIdx.x == 0) bsum[blockIdx.x] = s[0];
}

__global__ void scan_bsums(int* __restrict__ bsum, int nb) {
    __shared__ int s[512];
    int t = threadIdx.x;
    int v = (t < nb) ? bsum[t] : 0;
    s[t] = v;
    __syncthreads();
    for (int off = 1; off < 512; off <<= 1) {
        int add = (t >= off) ? s[t - off] : 0;
        __syncthreads();
        s[t] += add;
        __syncthreads();
    }
    if (t < nb) bsum[t] = s[t] - v;   // exclusive base per block
}

__global__ void scan_final(const int* __restrict__ deg, const int* __restrict__ bbase,
                           int* __restrict__ eoff, int n) {
    __shared__ int s[256];
    int i = blockIdx.x * 256 + threadIdx.x;
    int v = (i < n) ? deg[i] : 0;
    s[threadIdx.x] = v;
    __syncthreads();
    for (int off = 1; off < 256; off <<= 1) {
        int add = (threadIdx.x >= off) ? s[threadIdx.x - off] : 0;
        __syncthreads();
        s[threadIdx.x] += add;
        __syncthreads();
    }
    if (i < n) eoff[i + 1] = bbase[blockIdx.x] + s[threadIdx.x];
    if (i == 0) eoff[0] = 0;
}

// writes dst-sorted packed edges: epack[p] = {src, bits(eattr)}
__global__ void scatter_edges(const int* __restrict__ src, const int* __restrict__ dst,
                              const float* __restrict__ eattr,
                              const int* __restrict__ eoff,
                              int* __restrict__ cursor, int2* __restrict__ epack, int E) {
    int e = blockIdx.x * 256 + threadIdx.x;
    if (e >= E) return;
    int d = dst[e];
    int p = eoff[d] + atomicAdd(&cursor[d], 1);
    epack[p] = make_int2(src[e], __float_as_int(eattr[e]));
}

// ---------------------------------------------------------------- dense lins

// layer 1: [n,4] @ [4,128], fused with attn-coeff (8-lane shuffle reduction)
__global__ __launch_bounds__(256) void lin4_attn(const float* __restrict__ X,
                                                 const float* __restrict__ W,
                                                 const float* __restrict__ as_,
                                                 const float* __restrict__ ad_,
                                                 float* __restrict__ Y,
                                                 float* __restrict__ asrc,
                                                 float* __restrict__ adst, int n) {
    int gid = blockIdx.x * 256 + threadIdx.x;
    int node = gid >> 6;
    if (node >= n) return;
    int lane = threadIdx.x & 63;
    int c0 = lane * 2;
    float4 xv = *(const float4*)(X + (long)node * 4);
    float a0 = xv.x * W[c0]       + xv.y * W[128 + c0]     + xv.z * W[256 + c0]     + xv.w * W[384 + c0];
    float a1 = xv.x * W[c0 + 1]   + xv.y * W[128 + c0 + 1] + xv.z * W[256 + c0 + 1] + xv.w * W[384 + c0 + 1];
    *(float2*)(Y + (long)node * HCDIM + c0) = make_float2(a0, a1);

    int h = lane >> 3;
    int cc = c0 & 15;
    float ps = a0 * as_[h * CDIM + cc] + a1 * as_[h * CDIM + cc + 1];
    float pd = a0 * ad_[h * CDIM + cc] + a1 * ad_[h * CDIM + cc + 1];
    ps += __shfl_xor(ps, 1); ps += __shfl_xor(ps, 2); ps += __shfl_xor(ps, 4);
    pd += __shfl_xor(pd, 1); pd += __shfl_xor(pd, 2); pd += __shfl_xor(pd, 4);
    if ((lane & 7) == 0) {
        asrc[node * NHEAD + h] = ps;
        adst[node * NHEAD + h] = pd;
    }
}

// layers 2/3: [n,128] @ [128,144] via split-bf16 MFMA.
// cols 0..127 -> Y;  col-tile 8 (cols 128..143) -> next-layer attn coeffs
// (asrcn for l16<8, adstn for l16>=8) — same GEMM input, free fusion.
__global__ __launch_bounds__(256) void gemm_mfma(const unsigned short* __restrict__ Ahi,
                                                 const unsigned short* __restrict__ Alo,
                                                 const unsigned short* __restrict__ Wth,
                                                 const unsigned short* __restrict__ Wtl,
                                                 float* __restrict__ Y,
                                                 float* __restrict__ asrcn,
                                                 float* __restrict__ adstn, int n) {
    const int wave = threadIdx.x >> 6;
    const int lane = threadIdx.x & 63;
    const int quad = lane >> 4;
    const int l16  = lane & 15;
    const int rowbase = (blockIdx.x * 8 + wave * 2) * 16;

    f32x4 acc[2][9];
#pragma unroll
    for (int r = 0; r < 2; ++r)
#pragma unroll
        for (int t = 0; t < 9; ++t) acc[r][t] = (f32x4){0.f, 0.f, 0.f, 0.f};

#pragma unroll
    for (int kb = 0; kb < HCDIM; kb += 32) {
        short8 ah[2], al[2];
#pragma unroll
        for (int r = 0; r < 2; ++r) {
            int row = rowbase + r * 16 + l16;
            row = (row < n) ? row : (n - 1);
            const long off = (long)row * HCDIM + kb + quad * 8;
            ah[r] = *(const short8*)(Ahi + off);
            al[r] = *(const short8*)(Alo + off);
        }
#pragma unroll
        for (int nt = 0; nt < 9; ++nt) {
            const long woff = (long)(nt * 16 + l16) * HCDIM + kb + quad * 8;
            short8 bh = *(const short8*)(Wth + woff);
            short8 bl = *(const short8*)(Wtl + woff);
#pragma unroll
            for (int r = 0; r < 2; ++r) {
                acc[r][nt] = __builtin_amdgcn_mfma_f32_16x16x32_bf16(ah[r], bh, acc[r][nt], 0, 0, 0);
                acc[r][nt] = __builtin_amdgcn_mfma_f32_16x16x32_bf16(al[r], bh, acc[r][nt], 0, 0, 0);
                acc[r][nt] = __builtin_amdgcn_mfma_f32_16x16x32_bf16(ah[r], bl, acc[r][nt], 0, 0, 0);
            }
        }
    }

    // C/D layout: col = l16, row_local = quad*4 + reg
#pragma unroll
    for (int r = 0; r < 2; ++r) {
#pragma unroll
        for (int reg = 0; reg < 4; ++reg) {
            int row = rowbase + r * 16 + quad * 4 + reg;
            if (row < n) {
                float* yp = Y + (long)row * HCDIM + l16;
#pragma unroll
                for (int nt = 0; nt < 8; ++nt) yp[nt * 16] = acc[r][nt][reg];
                float cv = acc[r][8][reg];
                if (l16 < 8) asrcn[row * NHEAD + l16] = cv;
                else         adstn[row * NHEAD + (l16 - 8)] = cv;
            }
        }
    }
}

// ---------------------------------------------------------------- aggregate

// TWO nodes per wave (32 lanes x float4 channels each); single pass,
// no max-subtraction (alpha is O(1): exp(a)/sum exp(a) identical).
// floop (self-loop attr = mean eattr) computed in-wave from the edges.
__global__ __launch_bounds__(256) void gat_aggregate(
    const float* __restrict__ hlin,     // [n,128]
    const float* __restrict__ asrc,     // [n,8]
    const float* __restrict__ adst,     // [n,8]
    const int2*  __restrict__ epack,    // [E] dst-sorted {src, bits(eattr)}
    const int*   __restrict__ eoff,     // [n+1]
    const float* __restrict__ kc,       // [8] this layer
    const float* __restrict__ bias,     // [128]
    float* __restrict__ outf,           // [n,128] (split_out=0)
    unsigned short* __restrict__ outhi, // [n,128] (split_out=1)
    unsigned short* __restrict__ outlo,
    int n, int use_loop, int split_out) {
    const int lane = threadIdx.x & 63;
    const int hl = lane & 31;
    int nid = ((blockIdx.x * 256 + threadIdx.x) >> 6) * 2 + (lane >> 5);
    if (nid >= n) return;
    const int h = hl >> 2;            // 4 lanes per head
    const int c0 = hl * 4;            // 4 contiguous channels per lane

    const float adst_h = adst[nid * NHEAD + h];
    const float k_h = kc[h];
    const int e0 = eoff[nid], e1 = eoff[nid + 1];

    float den = 0.f, sume = 0.f;
    float ax = 0.f, ay = 0.f, az = 0.f, aw = 0.f;

    for (int base = e0; base < e1; base += 4) {
        int2 ep[4];
#pragma unroll
        for (int j = 0; j < 4; ++j) {
            int idx = base + j; idx = (idx < e1) ? idx : (e1 - 1);
            ep[j] = epack[idx];
        }
        float av[4]; float4 hv[4];
#pragma unroll
        for (int j = 0; j < 4; ++j) {
            av[j] = asrc[ep[j].x * NHEAD + h];
            hv[j] = *(const float4*)(hlin + (long)ep[j].x * HCDIM + c0);
        }
#pragma unroll
        for (int j = 0; j < 4; ++j) {
            bool valid = (base + j < e1);
            float ea = __int_as_float(ep[j].y);
            float a = av[j] + adst_h + ea * k_h;
            a = (a > 0.f) ? a : 0.2f * a;
            float w = valid ? __expf(a) : 0.f;
            sume += valid ? ea : 0.f;
            den += w;
            ax += hv[j].x * w; ay += hv[j].y * w; az += hv[j].z * w; aw += hv[j].w * w;
        }
    }

    if (use_loop) {   // self-loop; attr = mean of incoming eattr
        float fl = sume / fmaxf((float)(e1 - e0), 1.f);
        float a = asrc[nid * NHEAD + h] + adst_h + fl * k_h;
        a = (a > 0.f) ? a : 0.2f * a;
        float w = __expf(a);
        float4 hv = *(const float4*)(hlin + (long)nid * HCDIM + c0);
        den += w; ax += hv.x * w; ay += hv.y * w; az += hv.z * w; aw += hv.w * w;
    }

    float inv = 1.f / (den + 1e-16f);
    float4 bv = *(const float4*)(bias + c0);
    float o0 = fmaxf(ax * inv + bv.x, 0.f);
    float o1 = fmaxf(ay * inv + bv.y, 0.f);
    float o2 = fmaxf(az * inv + bv.z, 0.f);
    float o3 = fmaxf(aw * inv + bv.w, 0.f);
    if (split_out) {
        unsigned short h0 = f2bf(o0), h1 = f2bf(o1), h2 = f2bf(o2), h3 = f2bf(o3);
        ushort4 hi = make_ushort4(h0, h1, h2, h3);
        ushort4 lo = make_ushort4(f2bf(o0 - bf2f(h0)), f2bf(o1 - bf2f(h1)),
                                  f2bf(o2 - bf2f(h2)), f2bf(o3 - bf2f(h3)));
        *(ushort4*)(outhi + (long)nid * HCDIM + c0) = hi;
        *(ushort4*)(outlo + (long)nid * HCDIM + c0) = lo;
    } else {
        *(float4*)(outf + (long)nid * HCDIM + c0) = make_float4(o0, o1, o2, o3);
    }
}

// ---------------------------------------------------------------- pool + MLP

__global__ __launch_bounds__(128) void pool_kernel(const float* __restrict__ H,
                                                   const int* __restrict__ batch,
                                                   float* __restrict__ gsum, int n) {
    const int c = threadIdx.x;            // 0..127
    const int n0 = blockIdx.x * 128;
    if (n0 >= n) return;
    const int n1 = min(n0 + 128, n);
    float acc = 0.f;
    int cg = batch[n0];
    for (int i = n0; i < n1; ++i) {
        int g = batch[i];
        if (g != cg) {
            atomicAdd(&gsum[cg * HCDIM + c], acc);
            acc = 0.f;
            cg = g;
        }
        acc += H[(long)i * HCDIM + c];
    }
    atomicAdd(&gsum[cg * HCDIM + c], acc);
}

__global__ __launch_bounds__(64) void mlp_kernel(const float* __restrict__ gsum,
                                                 const int* __restrict__ gstart,
                                                 const float* __restrict__ fw1,
                                                 const float* __restrict__ fb1,
                                                 const float* __restrict__ fw2,
                                                 const float* __restrict__ fb2,
                                                 float* __restrict__ out) {
    const int g = blockIdx.x;
    const int j = threadIdx.x;            // 0..63
    __shared__ float emb[HCDIM];
    __shared__ float gh[64];
    int cnt = gstart[g + 1] - gstart[g];
    float invc = 1.f / fmaxf((float)cnt, 1.f);
    emb[j] = gsum[g * HCDIM + j] * invc;
    emb[j + 64] = gsum[g * HCDIM + 64 + j] * invc;
    __syncthreads();
    float a = fb1[j];
    for (int k = 0; k < HCDIM; ++k) a += emb[k] * fw1[k * 64 + j];
    gh[j] = fmaxf(a, 0.f);
    __syncthreads();
    if (j < 2) {
        float o = fb2[j];
        for (int k = 0; k < 64; ++k) o += gh[k] * fw2[k * 2 + j];
        out[g * 2 + j] = o;
    }
}

// ---------------------------------------------------------------- launcher

extern "C" void kernel_launch(void* const* d_in, const int* in_sizes, int n_in,
                              void* d_out, int out_size, void* d_ws, size_t ws_size,
                              hipStream_t stream) {
    const float* x     = (const float*)d_in[0];
    const int*   eidx  = (const int*)d_in[1];
    const float* eattr = (const float*)d_in[2];
    const int*   batch = (const int*)d_in[3];
    const float* w1  = (const float*)d_in[4];
    const float* as1 = (const float*)d_in[5];
    const float* ad1 = (const float*)d_in[6];
    const float* we1 = (const float*)d_in[7];
    const float* ae1 = (const float*)d_in[8];
    const float* b1  = (const float*)d_in[9];
    const float* w2  = (const float*)d_in[10];
    const float* as2 = (const float*)d_in[11];
    const float* ad2 = (const float*)d_in[12];
    const float* we2 = (const float*)d_in[13];
    const float* ae2 = (const float*)d_in[14];
    const float* b2  = (const float*)d_in[15];
    const float* w3  = (const float*)d_in[16];
    const float* as3 = (const float*)d_in[17];
    const float* ad3 = (const float*)d_in[18];
    const float* we3 = (const float*)d_in[19];
    const float* ae3 = (const float*)d_in[20];
    const float* b3  = (const float*)d_in[21];
    const float* fw1 = (const float*)d_in[22];
    const float* fb1 = (const float*)d_in[23];
    const float* fw2 = (const float*)d_in[24];
    const float* fb2 = (const float*)d_in[25];

    const int N = in_sizes[3];
    const int E = in_sizes[2];
    const int* src = eidx;
    const int* dst = eidx + E;

    // workspace carve
    char* p = (char*)d_ws;
    auto alloc = [&](size_t bytes) {
        void* r = (void*)p;
        p += (bytes + 255) & ~(size_t)255;
        return r;
    };
    float* A      = (float*)alloc((size_t)N * HCDIM * 4);
    // B region: bf16 hi/lo pair (layers 1-2) ALIASED with fp32 (layer 3 -> pool).
    char*  Bbuf   = (char*)alloc((size_t)N * HCDIM * 4);
    unsigned short* Bhi = (unsigned short*)Bbuf;
    unsigned short* Blo = Bhi + (size_t)N * HCDIM;
    float* Bf32   = (float*)Bbuf;
    float* asrcA  = (float*)alloc((size_t)N * NHEAD * 4);
    float* adstA  = (float*)alloc((size_t)N * NHEAD * 4);
    float* asrcB  = (float*)alloc((size_t)N * NHEAD * 4);
    float* adstB  = (float*)alloc((size_t)N * NHEAD * 4);
    int*   deg    = (int*)alloc((size_t)N * 4);
    int*   eoff   = (int*)alloc((size_t)(N + 1) * 4);
    int*   cursor = (int*)alloc((size_t)N * 4);
    int2*  epack  = (int2*)alloc((size_t)E * 8);
    int*   bsum   = (int*)alloc(((size_t)(N + 255) / 256) * 4);
    float* kc     = (float*)alloc(24 * 4);
    int*   gstart = (int*)alloc((NGRAPH + 1) * 4);
    float* gsum   = (float*)alloc(NGRAPH * HCDIM * 4);
    unsigned short* wt2h = (unsigned short*)alloc(WEXT * HCDIM * 2);
    unsigned short* wt2l = (unsigned short*)alloc(WEXT * HCDIM * 2);
    unsigned short* wt3h = (unsigned short*)alloc(WEXT * HCDIM * 2);
    unsigned short* wt3l = (unsigned short*)alloc(WEXT * HCDIM * 2);

    const int NB = (N + 255) / 256;
    const int EB = (E + 255) / 256;
    const int AGG_BLOCKS = (((N + 1) / 2) * 64 + 255) / 256;   // 2 nodes/wave
    const int GEMM_BLOCKS = (N + 127) / 128;                   // 128 rows per block

    setup0<<<NB, 256, 0, stream>>>(deg, cursor, gsum,
                                   w2, w3, wt2h, wt2l, wt3h, wt3l,
                                   we1, ae1, we2, ae2, we3, ae3, kc,
                                   as2, ad2, as3, ad3,
                                   batch, gstart, N);
    count_deg<<<EB, 256, 0, stream>>>(dst, deg, E);
    block_sum<<<NB, 256, 0, stream>>>(deg, bsum, N);
    scan_bsums<<<1, 512, 0, stream>>>(bsum, NB);
    scan_final<<<NB, 256, 0, stream>>>(deg, bsum, eoff, N);
    scatter_edges<<<EB, 256, 0, stream>>>(src, dst, eattr, eoff, cursor, epack, E);

    // layer 1 (no self loops): lin + layer-1 attn coeffs fused
    lin4_attn<<<(N * 64 + 255) / 256, 256, 0, stream>>>(x, w1, as1, ad1, A, asrcA, adstA, N);
    gat_aggregate<<<AGG_BLOCKS, 256, 0, stream>>>(A, asrcA, adstA, epack, eoff,
                                                  kc + 0, b1, Bf32, Bhi, Blo, N, 0, 1);
    // layer 2: gemm emits h2 + layer-2 coeffs (from extended W2)
    gemm_mfma<<<GEMM_BLOCKS, 256, 0, stream>>>(Bhi, Blo, wt2h, wt2l, A, asrcB, adstB, N);
    gat_aggregate<<<AGG_BLOCKS, 256, 0, stream>>>(A, asrcB, adstB, epack, eoff,
                                                  kc + 8, b2, Bf32, Bhi, Blo, N, 1, 1);
    // layer 3: gemm emits h3 + layer-3 coeffs (from extended W3)
    gemm_mfma<<<GEMM_BLOCKS, 256, 0, stream>>>(Bhi, Blo, wt3h, wt3l, A, asrcA, adstA, N);
    gat_aggregate<<<AGG_BLOCKS, 256, 0, stream>>>(A, asrcA, adstA, epack, eoff,
                                                  kc + 16, b3, Bf32, Bhi, Blo, N, 1, 0);

    // mean-pool + MLP head
    pool_kernel<<<(N + 127) / 128, 128, 0, stream>>>(Bf32, batch, gsum, N);
    mlp_kernel<<<NGRAPH, 64, 0, stream>>>(gsum, gstart, fw1, fb1, fw2, fb2, (float*)d_out);
}